// Round 8
// baseline (257.906 us; speedup 1.0000x reference)
//
#include <hip/hip_runtime.h>
#include <hip/hip_bf16.h>
#include <stdint.h>

typedef __hip_bfloat16 bf16;
typedef __attribute__((ext_vector_type(4))) short short4v;
typedef __attribute__((ext_vector_type(8))) short short8v;
typedef __attribute__((ext_vector_type(4))) float f32x4;

#define CAT8(lo,hi) __builtin_shufflevector(lo, hi, 0,1,2,3,4,5,6,7)
#define MFMA16(a,b,c) __builtin_amdgcn_mfma_f32_16x16x32_bf16(a,b,c,0,0,0)

__device__ __forceinline__ void gload16(const void* g, void* l) {
  __builtin_amdgcn_global_load_lds((const __attribute__((address_space(1))) unsigned int*)g,
                                   (__attribute__((address_space(3))) unsigned int*)l, 16, 0, 0);
}

__device__ __forceinline__ short f2bs(float f) {
  return __builtin_bit_cast(short, __float2bfloat16(f));
}

// byte-offset swizzle within a 128-B LDS row (8 x 16-B chunks): chunk ^= row&7
#define SWZ(b,row) (((b)&15) | ((((((b)>>4)) ^ ((row)&7)) & 7)<<4))

// compiler-fence-bracketed raw barrier (keeps IR loads from crossing)
#define BAR() do { asm volatile("" ::: "memory"); __builtin_amdgcn_s_barrier(); \
                   asm volatile("" ::: "memory"); } while (0)

// ---------------- convert x (f32 -> bf16), 4 elems/thread ----------------
__global__ __launch_bounds__(256) void k_cvt_x(const float* __restrict__ in, bf16* __restrict__ out) {
  int i = blockIdx.x*256 + threadIdx.x;
  float4 v = ((const float4*)in)[i];
  bf16* o = out + (size_t)i*4;
  o[0] = __float2bfloat16(v.x); o[1] = __float2bfloat16(v.y);
  o[2] = __float2bfloat16(v.z); o[3] = __float2bfloat16(v.w);
}

// ---------------- transpose-convert: W[K][N] f32 -> Wt[N][K] bf16 ----------------
__global__ __launch_bounds__(256) void k_transpose_cvt(const float* __restrict__ W, bf16* __restrict__ Wt,
                                                       int K, int N) {
  __shared__ float ts[64][65];
  int k0 = blockIdx.y*64, n0 = blockIdx.x*64;
  int t = threadIdx.x;
  #pragma unroll
  for (int ii = 0; ii < 16; ++ii) {
    int idx = ii*256 + t; int r = idx>>6, c = idx&63;
    ts[r][c] = W[(size_t)(k0+r)*N + n0 + c];
  }
  __syncthreads();
  #pragma unroll
  for (int ii = 0; ii < 16; ++ii) {
    int idx = ii*256 + t; int r = idx>>6, c = idx&63;   // r: n-row, c: k-col
    Wt[(size_t)(n0+r)*K + k0 + c] = __float2bfloat16(ts[c][r]);
  }
}

// ---------------- 256x256 split-K GEMM, BK=64, 8 waves, 4-phase derived-waits ----------------
// Per K-tile: 4 phases {kk,ih}, 16 MFMA each. Each phase first issues ONE half-tile
// stage of tile t+1 (order B0,B1,A0,A1 into buf^1). Derived counted gates:
//   ph0 gate vmcnt(4): newest needed = A0(t); issued after it: A1(t)+B0(t+1) = 4 loads
//   ph1 gate vmcnt(4): newest needed = A1(t); after: B0(t+1)+B1(t+1) = 4 loads
//   ph2/ph3: no new half-tiles consumed -> no gate, no barrier
//   end-of-tile barrier: all waves done reading buf before next iter stages into it
// vmcnt never 0 in steady state (last tile drains 2 -> 0).
__global__ __launch_bounds__(512, 2) void k_gemm256(const bf16* __restrict__ A, const bf16* __restrict__ Bt,
                                                    float* __restrict__ C, int M, int N, int K,
                                                    int KC, int ldc) {
  __shared__ __align__(1024) bf16 lds[2][2][256*64];   // [dbuf][A=0/B=1][row][k]
  const int t = threadIdx.x;
  const int lane = t & 63, w = t >> 6;
  const int wr = w >> 2, wc = w & 3;                   // 2 (M) x 4 (N) waves
  const int l15 = lane & 15;
  const int kb  = (lane >> 4) << 2;                    // k-quad base of lane group

  // --- XCD-chunked block-id swizzle (bijective; nwg % 8 == 0) ---
  const int nbx = gridDim.x, nby = gridDim.y;
  const int nwg = nbx*nby*gridDim.z;
  int bid = (blockIdx.z*nby + blockIdx.y)*nbx + blockIdx.x;
  int newid = (bid & 7)*(nwg >> 3) + (bid >> 3);
  int z   = newid / (nbx*nby);
  int rem = newid - z*(nbx*nby);
  const int m0 = (rem / nbx) * 256;
  const int n0 = (rem % nbx) * 256;
  const int kbeg = z * KC;

  f32x4 acc[8][4];
  #pragma unroll
  for (int i = 0; i < 8; ++i)
    #pragma unroll
    for (int j = 0; j < 4; ++j) acc[i][j] = 0.f;

  const char* Ab = (const char*)A;
  const char* Bb = (const char*)Bt;
  const int off = t*16;                                // this thread's linear slot

  // stage one HALF-tile (128 rows x 64 k = 16 KB): 2 gloads/thread
#define STG(buf, op, rowbase, gp, h, k0) do {                                      \
    int d0 = off + (h)*16384;                                                      \
    int r0 = d0 >> 7;                                                              \
    int s0 = (((d0 >> 4) & 7) ^ (r0 & 7)) << 4;                                    \
    gload16((gp) + ((size_t)((rowbase)+r0)*K + (k0))*2 + s0, (char*)lds[buf][op] + d0); \
    int d1 = d0 + 8192;                                                            \
    int r1 = d1 >> 7;                                                              \
    int s1 = (((d1 >> 4) & 7) ^ (r1 & 7)) << 4;                                    \
    gload16((gp) + ((size_t)((rowbase)+r1)*K + (k0))*2 + s1, (char*)lds[buf][op] + d1); \
  } while (0)

#define BFRAGS(bfr, kkk) do {                                                      \
    const int lob_ = (kkk)*64 + (kb << 1);                                         \
    _Pragma("unroll")                                                              \
    for (int j_ = 0; j_ < 4; ++j_) {                                               \
      const int row_ = wc*64 + j_*16 + l15;                                        \
      const char* bp_ = Bc + row_*128;                                             \
      bfr[j_] = CAT8(*(const short4v*)(bp_ + SWZ(lob_, row_)),                     \
                     *(const short4v*)(bp_ + SWZ(lob_ + 32, row_)));               \
    }                                                                              \
  } while (0)

#define AMFMA(ihh, kkk, bfr) do {                                                  \
    const int lob_ = (kkk)*64 + (kb << 1);                                         \
    short8v a_[4];                                                                 \
    _Pragma("unroll")                                                              \
    for (int i_ = 0; i_ < 4; ++i_) {                                               \
      const int row_ = wr*128 + ((ihh)*4 + i_)*16 + l15;                           \
      const char* ap_ = Ac + row_*128;                                             \
      a_[i_] = CAT8(*(const short4v*)(ap_ + SWZ(lob_, row_)),                      \
                    *(const short4v*)(ap_ + SWZ(lob_ + 32, row_)));                \
    }                                                                              \
    __builtin_amdgcn_s_setprio(1);                                                 \
    _Pragma("unroll")                                                              \
    for (int i_ = 0; i_ < 4; ++i_)                                                 \
      _Pragma("unroll")                                                            \
      for (int j_ = 0; j_ < 4; ++j_)                                               \
        acc[(ihh)*4 + i_][j_] = MFMA16(a_[i_], bfr[j_], acc[(ihh)*4 + i_][j_]);    \
    __builtin_amdgcn_s_setprio(0);                                                 \
  } while (0)

  const int ntiles = KC >> 6;
  // prologue: tile 0 half-tiles in steady-state order B0,B1,A0,A1
  STG(0, 1, n0, Bb, 0, kbeg);
  STG(0, 1, n0, Bb, 1, kbeg);
  STG(0, 0, m0, Ab, 0, kbeg);
  STG(0, 0, m0, Ab, 1, kbeg);

  for (int it = 0; it < ntiles; ++it) {
    const int buf = it & 1;
    const bool pf = (it + 1 < ntiles);
    const int knx = kbeg + (it + 1)*64;
    const char* Ac = (const char*)lds[buf][0];
    const char* Bc = (const char*)lds[buf][1];
    short8v bfr0[4], bfr1[4];

    // ---- phase 0: kk=0, A-half 0 ----
    if (pf) { STG(buf^1, 1, n0, Bb, 0, knx);
              asm volatile("s_waitcnt vmcnt(4)" ::: "memory"); }
    else    { asm volatile("s_waitcnt vmcnt(2)" ::: "memory"); }
    BAR();
    __builtin_amdgcn_sched_barrier(0);
    BFRAGS(bfr0, 0);
    AMFMA(0, 0, bfr0);

    // ---- phase 1: kk=0, A-half 1 ----
    if (pf) { STG(buf^1, 1, n0, Bb, 1, knx);
              asm volatile("s_waitcnt vmcnt(4)" ::: "memory"); }
    else    { asm volatile("s_waitcnt vmcnt(0)" ::: "memory"); }
    BAR();
    __builtin_amdgcn_sched_barrier(0);
    AMFMA(1, 0, bfr0);

    // ---- phase 2: kk=1, A-half 0 (no new half-tiles consumed: no gate) ----
    if (pf) STG(buf^1, 0, m0, Ab, 0, knx);
    BFRAGS(bfr1, 1);
    AMFMA(0, 1, bfr1);

    // ---- phase 3: kk=1, A-half 1 ----
    if (pf) STG(buf^1, 0, m0, Ab, 1, knx);
    AMFMA(1, 1, bfr1);

    __builtin_amdgcn_sched_barrier(0);
    BAR();   // end-of-tile: buf fully read by all waves before next iter stages into it
  }
#undef STG
#undef BFRAGS
#undef AMFMA

  #pragma unroll
  for (int i = 0; i < 8; ++i) {
    int row0 = m0 + wr*128 + i*16 + ((lane>>4)<<2);
    #pragma unroll
    for (int j = 0; j < 4; ++j) {
      int col = n0 + wc*64 + j*16 + l15;
      #pragma unroll
      for (int r = 0; r < 4; ++r)
        atomicAdd(&C[(size_t)(row0+r)*ldc + col], acc[i][j][r]);
    }
  }
}

// ---------------- fused RMSNorm + RoPE; V transpose-convert (reads f32 QKV) ----------------
__global__ __launch_bounds__(256) void k_normrope(const float* __restrict__ qkv,
    const float* __restrict__ cosb, const float* __restrict__ sinb,
    const float* __restrict__ qg, const float* __restrict__ kg,
    bf16* __restrict__ Qb, bf16* __restrict__ Kb, bf16* __restrict__ Vt) {
  int wid = blockIdx.x*4 + (threadIdx.x>>6);
  int lane = threadIdx.x & 63;
  int s = wid / 48, r = wid - s*48;
  int col;
  if (r < 32) col = r*64;
  else if (r < 40) col = 2048 + (r-32)*64;
  else col = 2560 + (r-40)*64;
  float v = qkv[(size_t)s*3072 + col + lane];
  if (r < 40) {
    float ss = v*v;
    #pragma unroll
    for (int o = 32; o; o >>= 1) ss += __shfl_xor(ss, o);
    float rms = rsqrtf(ss*(1.0f/64.0f) + 1e-6f);
    float g = (r < 32 ? qg : kg)[lane];
    float tn = v*rms*g;
    float other = __shfl_xor(tn, 32);
    float rot = (lane < 32) ? -other : other;
    float outv = tn*cosb[s*64+lane] + rot*sinb[s*64+lane];
    if (r < 32) Qb[((size_t)r*2048 + s)*64 + lane] = __float2bfloat16(outv);
    else        Kb[((size_t)(r-32)*2048 + s)*64 + lane] = __float2bfloat16(outv);
  } else {
    Vt[(size_t)(r-40)*64*2048 + (size_t)lane*2048 + s] = __float2bfloat16(v);
  }
}

// ---------------- causal flash attention v3: swapped-operand in-register softmax ----
#define SCALE2 0.18033688011f   /* (1/sqrt(64)) * log2(e) */
__global__ __launch_bounds__(512) void k_attn(const bf16* __restrict__ Qb, const bf16* __restrict__ Kb,
                                              const bf16* __restrict__ Vt, bf16* __restrict__ attnb) {
  __shared__ bf16 Ksm[64][68];
  __shared__ bf16 Vsm[64][68];
  const int t = threadIdx.x, lane = t & 63, w = t >> 6;
  const int bid = blockIdx.x;
  const int h = bid & 31;
  const int qi = 15 - (bid >> 5);          // heavy blocks first
  const int qb0 = qi * 128;
  const int kvh = h >> 2;
  const int kb = (lane>>4)*4;
  const int l15 = lane & 15;

  const bf16* Qh = Qb + (size_t)h*2048*64;
  const bf16* Kh = Kb + (size_t)kvh*2048*64;
  const bf16* Vh = Vt + (size_t)kvh*64*2048;

  const int qrow = qb0 + w*16 + l15;       // this lane's q-row (replicated x4 groups)
  short4v qlo[2], qhi[2];
  #pragma unroll
  for (int kk = 0; kk < 2; ++kk) {
    qlo[kk] = *(const short4v*)(Qh + (size_t)qrow*64 + kk*32 + kb);
    qhi[kk] = *(const short4v*)(Qh + (size_t)qrow*64 + kk*32 + 16 + kb);
  }

  float m_ = -3e38f, ls = 0.f;
  f32x4 o2[4];
  #pragma unroll
  for (int j = 0; j < 4; ++j) o2[j] = 0.f;

  const int srow = t >> 3;                 // staging: 512 thr, 1 int4 each for K and V
  const int sc8  = (t & 7) * 8;

  const int nt = 2*qi + 2;
  for (int tt = 0; tt < nt; ++tt) {
    *(int4*)(&Ksm[srow][sc8]) = *(const int4*)(Kh + ((size_t)(tt*64 + srow))*64 + sc8);
    *(int4*)(&Vsm[srow][sc8]) = *(const int4*)(Vh + (size_t)srow*2048 + tt*64 + sc8);
    __syncthreads();

    // S^T = K Q^T -> sAcc[j]: kv-block j, q = l15
    f32x4 sAcc[4];
    #pragma unroll
    for (int j = 0; j < 4; ++j) sAcc[j] = 0.f;
    __builtin_amdgcn_s_setprio(1);
    #pragma unroll
    for (int kk = 0; kk < 2; ++kk) {
      short8v bq = CAT8(qlo[kk], qhi[kk]);
      #pragma unroll
      for (int j = 0; j < 4; ++j) {
        const bf16* kp = &Ksm[j*16 + l15][kk*32 + kb];
        short8v ak = CAT8(*(const short4v*)kp, *(const short4v*)(kp + 16));
        sAcc[j] = MFMA16(ak, bq, sAcc[j]);
      }
    }
    __builtin_amdgcn_s_setprio(0);

    float p[4][4];
    #pragma unroll
    for (int j = 0; j < 4; ++j)
      #pragma unroll
      for (int r = 0; r < 4; ++r) p[j][r] = sAcc[j][r]*SCALE2;
    if (tt*64 + 63 > qb0 + w*16) {
      #pragma unroll
      for (int j = 0; j < 4; ++j) {
        #pragma unroll
        for (int r = 0; r < 4; ++r)
          if (tt*64 + j*16 + kb + r > qrow) p[j][r] = -3e38f;
      }
    }

    float mx = p[0][0];
    #pragma unroll
    for (int j = 0; j < 4; ++j)
      #pragma unroll
      for (int r = 0; r < 4; ++r) mx = fmaxf(mx, p[j][r]);
    mx = fmaxf(mx, __shfl_xor(mx, 16));
    mx = fmaxf(mx, __shfl_xor(mx, 32));
    float mn = fmaxf(m_, mx);
    float alpha = exp2f(m_ - mn);
    m_ = mn;
    ls *= alpha;
    #pragma unroll
    for (int j = 0; j < 4; ++j) o2[j] *= alpha;

    float rs = 0.f;
    #pragma unroll
    for (int j = 0; j < 4; ++j)
      #pragma unroll
      for (int r = 0; r < 4; ++r) {
        float e = exp2f(p[j][r] - mn);
        p[j][r] = e;
        rs += e;
      }
    rs += __shfl_xor(rs, 16);
    rs += __shfl_xor(rs, 32);
    ls += rs;

    short8v pb[2];
    #pragma unroll
    for (int kk = 0; kk < 2; ++kk) {
      short8v v;
      v[0] = f2bs(p[2*kk][0]);   v[1] = f2bs(p[2*kk][1]);
      v[2] = f2bs(p[2*kk][2]);   v[3] = f2bs(p[2*kk][3]);
      v[4] = f2bs(p[2*kk+1][0]); v[5] = f2bs(p[2*kk+1][1]);
      v[6] = f2bs(p[2*kk+1][2]); v[7] = f2bs(p[2*kk+1][3]);
      pb[kk] = v;
    }

    // O^T += V^T P -> o2[j]: d-block j, q = l15
    __builtin_amdgcn_s_setprio(1);
    #pragma unroll
    for (int kk = 0; kk < 2; ++kk) {
      #pragma unroll
      for (int j = 0; j < 4; ++j) {
        const bf16* vp = &Vsm[j*16 + l15][kk*32 + kb];
        short8v av = CAT8(*(const short4v*)vp, *(const short4v*)(vp + 16));
        o2[j] = MFMA16(av, pb[kk], o2[j]);
      }
    }
    __builtin_amdgcn_s_setprio(0);
    __syncthreads();
  }

  float inv = 1.0f / ls;
  #pragma unroll
  for (int j = 0; j < 4; ++j)
    #pragma unroll
    for (int r = 0; r < 4; ++r)
      attnb[(size_t)qrow*2048 + h*64 + j*16 + kb + r] = __float2bfloat16(o2[j][r]*inv);
}

extern "C" void kernel_launch(void* const* d_in, const int* in_sizes, int n_in,
                              void* d_out, int out_size, void* d_ws, size_t ws_size,
                              hipStream_t stream) {
  const float* x    = (const float*)d_in[0];
  const float* cosb = (const float*)d_in[2];
  const float* sinb = (const float*)d_in[3];
  const float* Wq   = (const float*)d_in[4];
  const float* Wk   = (const float*)d_in[5];
  const float* Wv   = (const float*)d_in[6];
  const float* Wo   = (const float*)d_in[7];
  const float* qg   = (const float*)d_in[8];
  const float* kg   = (const float*)d_in[9];
  float* out = (float*)d_out;

  char* ws = (char*)d_ws;
  // phase 1-2 layout
  bf16*  xb    = (bf16*)(ws);                    // 8 MB    [2048][2048]
  bf16*  WqT   = (bf16*)(ws + 8388608);          // 8 MB    [2048][2048]
  bf16*  WkT   = (bf16*)(ws + 16777216);         // 2 MB
  bf16*  WvT   = (bf16*)(ws + 18874368);         // 2 MB
  bf16*  WoT   = (bf16*)(ws + 20971520);         // 8 MB    (live until out-proj)
  float* QKVf  = (float*)(ws + 29360128);        // 25.2 MB [2048][3072] f32 (atomic target)
  // phase 3-4 layout (overlays dead xb/WqT/WkT/WvT)
  bf16*  Qb    = (bf16*)(ws);                    // 8 MB    [32][2048][64]
  bf16*  Kb    = (bf16*)(ws + 8388608);          // 2 MB    [8][2048][64]
  bf16*  Vt    = (bf16*)(ws + 10485760);         // 2 MB    [8][64][2048]
  bf16*  attnb = (bf16*)(ws + 29360128);         // 8 MB    (overlays dead QKVf)

  hipMemsetAsync(QKVf, 0, 25165824, stream);
  hipMemsetAsync(out, 0, (size_t)out_size*4, stream);

  k_cvt_x<<<4096, 256, 0, stream>>>(x, xb);
  k_transpose_cvt<<<dim3(32, 32), 256, 0, stream>>>(Wq, WqT, 2048, 2048);
  k_transpose_cvt<<<dim3(8, 32),  256, 0, stream>>>(Wk, WkT, 2048, 512);
  k_transpose_cvt<<<dim3(8, 32),  256, 0, stream>>>(Wv, WvT, 2048, 512);
  k_transpose_cvt<<<dim3(32, 32), 256, 0, stream>>>(Wo, WoT, 2048, 2048);

  // QKV projection: 256x256 tiles, split-K x2 -> 192 blocks (%8==0)
  k_gemm256<<<dim3(12, 8, 2), 512, 0, stream>>>(xb, WqT, QKVf, 2048, 3072, 2048, 1024, 3072);
  k_normrope<<<24576, 256, 0, stream>>>(QKVf, cosb, sinb, qg, kg, Qb, Kb, Vt);
  k_attn<<<512, 512, 0, stream>>>(Qb, Kb, Vt, attnb);
  // output projection: 256x256 tiles, split-K x4 -> 256 blocks (%8==0)
  k_gemm256<<<dim3(8, 8, 4), 512, 0, stream>>>(attnb, WoT, out, 2048, 2048, 2048, 512, 2048);
}

// Round 9
// 211.818 us; speedup vs baseline: 1.2176x; 1.2176x over previous
//
#include <hip/hip_runtime.h>
#include <hip/hip_bf16.h>
#include <stdint.h>

typedef __hip_bfloat16 bf16;
typedef __attribute__((ext_vector_type(4))) short short4v;
typedef __attribute__((ext_vector_type(8))) short short8v;
typedef __attribute__((ext_vector_type(4))) float f32x4;

#define CAT8(lo,hi) __builtin_shufflevector(lo, hi, 0,1,2,3,4,5,6,7)
#define MFMA16(a,b,c) __builtin_amdgcn_mfma_f32_16x16x32_bf16(a,b,c,0,0,0)

__device__ __forceinline__ void gload16(const void* g, void* l) {
  __builtin_amdgcn_global_load_lds((const __attribute__((address_space(1))) unsigned int*)g,
                                   (__attribute__((address_space(3))) unsigned int*)l, 16, 0, 0);
}

__device__ __forceinline__ short f2bs(float f) {
  return __builtin_bit_cast(short, __float2bfloat16(f));
}

// ---------------- convert x (f32 -> bf16), 4 elems/thread ----------------
__global__ __launch_bounds__(256) void k_cvt_x(const float* __restrict__ in, bf16* __restrict__ out) {
  int i = blockIdx.x*256 + threadIdx.x;
  float4 v = ((const float4*)in)[i];
  bf16* o = out + (size_t)i*4;
  o[0] = __float2bfloat16(v.x); o[1] = __float2bfloat16(v.y);
  o[2] = __float2bfloat16(v.z); o[3] = __float2bfloat16(v.w);
}

// ---------------- transpose-convert: W[K][N] f32 -> Wt[N][K] bf16 ----------------
__global__ __launch_bounds__(256) void k_transpose_cvt(const float* __restrict__ W, bf16* __restrict__ Wt,
                                                       int K, int N) {
  __shared__ float ts[64][65];
  int k0 = blockIdx.y*64, n0 = blockIdx.x*64;
  int t = threadIdx.x;
  #pragma unroll
  for (int ii = 0; ii < 16; ++ii) {
    int idx = ii*256 + t; int r = idx>>6, c = idx&63;
    ts[r][c] = W[(size_t)(k0+r)*N + n0 + c];
  }
  __syncthreads();
  #pragma unroll
  for (int ii = 0; ii < 16; ++ii) {
    int idx = ii*256 + t; int r = idx>>6, c = idx&63;   // r: n-row, c: k-col
    Wt[(size_t)(n0+r)*K + k0 + c] = __float2bfloat16(ts[c][r]);
  }
}

// ---------------- QKV GEMM with FUSED RMSNorm+RoPE epilogue ----------------
// 128x128 tile, BK=32, 4 waves 2x2, R6-proven 2-phase dbuf + vmcnt(4) skeleton.
// Full K per block (no split-K -> f32 acc is the complete projection, required
// for the fused norm). Each wave's 64-col span = exactly ONE head: rmsnorm =
// 4 squares + 4 shfl_xor (within l15 group); RoPE partner (col+-32) = j+-2 regs
// of the SAME lane. Epilogue writes Qb [32][S][64], Kb [8][S][64], Vb [8][S][64].
__global__ __launch_bounds__(256) void k_gemm_qkv(const bf16* __restrict__ A, const bf16* __restrict__ Bt,
                                                  const float* __restrict__ cosb, const float* __restrict__ sinb,
                                                  const float* __restrict__ qg, const float* __restrict__ kg,
                                                  bf16* __restrict__ Qb, bf16* __restrict__ Kb,
                                                  bf16* __restrict__ Vb, int K) {
  __shared__ bf16 Asm[2][128*32];
  __shared__ bf16 Bsm[2][128*32];
  const int t = threadIdx.x;
  const int lane = t & 63, w = t >> 6;
  const int wr = w >> 1, wc = w & 1;
  const int m0 = blockIdx.y*128, n0 = blockIdx.x*128;
  const int l15 = lane & 15;
  const int g8 = (lane >> 4) << 3;

  f32x4 acc[4][4];
  #pragma unroll
  for (int i = 0; i < 4; ++i)
    #pragma unroll
    for (int j = 0; j < 4; ++j) acc[i][j] = 0.f;

  const char* Ab = (const char*)A;
  const char* Bb = (const char*)Bt;
  const int off  = t*16;
  const int srow = off >> 6;
  const int scolb = (((off >> 4) & 3) ^ ((srow >> 1) & 3)) << 4;

  const size_t arow0 = (size_t)(m0+srow)*K, arow1 = (size_t)(m0+srow+64)*K;
  const size_t brow0 = (size_t)(n0+srow)*K, brow1 = (size_t)(n0+srow+64)*K;

#define STAGE(buf, kk)  do {                                          \
    gload16(Ab + (arow0 + (kk))*2 + scolb, (char*)Asm[buf] + off);    \
    gload16(Ab + (arow1 + (kk))*2 + scolb, (char*)Asm[buf] + off + 4096); \
    gload16(Bb + (brow0 + (kk))*2 + scolb, (char*)Bsm[buf] + off);    \
    gload16(Bb + (brow1 + (kk))*2 + scolb, (char*)Bsm[buf] + off + 4096); \
  } while (0)

  STAGE(0, 0);
  int cur = 0;

  for (int k0 = 0; k0 < K; k0 += 32) {
    if (k0 + 32 < K) {
      STAGE(cur ^ 1, k0 + 32);
      asm volatile("s_waitcnt vmcnt(4)" ::: "memory");
    } else {
      asm volatile("s_waitcnt vmcnt(0)" ::: "memory");
    }
    __builtin_amdgcn_s_barrier();
    __builtin_amdgcn_sched_barrier(0);

    const bf16* Ac = Asm[cur];
    const bf16* Bc = Bsm[cur];
    short4v alo[4], ahi[4], blo[4], bhi[4];
    #pragma unroll
    for (int i = 0; i < 4; ++i) {
      const int arow = wr*64 + i*16 + l15;
      const int asw  = ((arow >> 1) & 3) << 4;
      const char* ap = (const char*)Ac + arow*64;
      alo[i] = *(const short4v*)(ap + (g8 ^ asw));
      ahi[i] = *(const short4v*)(ap + ((32 + g8) ^ asw));
      const int brow = wc*64 + i*16 + l15;
      const int bsw  = ((brow >> 1) & 3) << 4;
      const char* bp = (const char*)Bc + brow*64;
      blo[i] = *(const short4v*)(bp + (g8 ^ bsw));
      bhi[i] = *(const short4v*)(bp + ((32 + g8) ^ bsw));
    }
    #pragma unroll
    for (int i = 0; i < 4; ++i) {
      short8v a = CAT8(alo[i], ahi[i]);
      #pragma unroll
      for (int j = 0; j < 4; ++j) {
        short8v b = CAT8(blo[j], bhi[j]);
        acc[i][j] = MFMA16(a, b, acc[i][j]);
      }
    }
    __builtin_amdgcn_sched_barrier(0);
    __builtin_amdgcn_s_barrier();
    cur ^= 1;
  }
#undef STAGE

  // ---- fused epilogue: rmsnorm + rope (Q/K) or plain cvt (V) ----
  const int hh = (n0 + wc*64) >> 6;            // head id 0..47 (wave-uniform)
  float gam[4];
  if (hh < 40) {
    const float* gp = (hh < 32) ? qg : kg;
    #pragma unroll
    for (int j = 0; j < 4; ++j) gam[j] = gp[j*16 + l15];
  }
  #pragma unroll
  for (int i = 0; i < 4; ++i) {
    #pragma unroll
    for (int rr = 0; rr < 4; ++rr) {
      const int row = m0 + wr*64 + i*16 + ((lane>>4)<<2) + rr;   // absolute s
      float v0 = acc[i][0][rr], v1 = acc[i][1][rr], v2 = acc[i][2][rr], v3 = acc[i][3][rr];
      if (hh < 40) {
        float ss = v0*v0 + v1*v1 + v2*v2 + v3*v3;
        ss += __shfl_xor(ss, 1); ss += __shfl_xor(ss, 2);
        ss += __shfl_xor(ss, 4); ss += __shfl_xor(ss, 8);
        const float rms = rsqrtf(ss*(1.0f/64.0f) + 1e-6f);
        const float t0 = v0*rms*gam[0], t1 = v1*rms*gam[1];
        const float t2 = v2*rms*gam[2], t3 = v3*rms*gam[3];
        const float* cr = cosb + (size_t)row*64;
        const float* sr = sinb + (size_t)row*64;
        const float o0 = t0*cr[l15]      - t2*sr[l15];
        const float o1 = t1*cr[16+l15]   - t3*sr[16+l15];
        const float o2 = t2*cr[32+l15]   + t0*sr[32+l15];
        const float o3 = t3*cr[48+l15]   + t1*sr[48+l15];
        bf16* dst = (hh < 32) ? (Qb + ((size_t)hh*2048 + row)*64)
                              : (Kb + ((size_t)(hh-32)*2048 + row)*64);
        dst[l15]      = __float2bfloat16(o0);
        dst[16 + l15] = __float2bfloat16(o1);
        dst[32 + l15] = __float2bfloat16(o2);
        dst[48 + l15] = __float2bfloat16(o3);
      } else {
        bf16* dst = Vb + ((size_t)(hh-40)*2048 + row)*64;
        dst[l15]      = __float2bfloat16(v0);
        dst[16 + l15] = __float2bfloat16(v1);
        dst[32 + l15] = __float2bfloat16(v2);
        dst[48 + l15] = __float2bfloat16(v3);
      }
    }
  }
}

// ---------------- out-proj GEMM: R6-proven split-K (128^2, 2-phase dbuf, swizzle) ----------------
__global__ __launch_bounds__(256) void k_gemm_out(const bf16* __restrict__ A, const bf16* __restrict__ Bt,
                                                  float* __restrict__ C, int M, int N, int K,
                                                  int KC, int ldc) {
  __shared__ bf16 Asm[2][128*32];
  __shared__ bf16 Bsm[2][128*32];
  const int t = threadIdx.x;
  const int lane = t & 63, w = t >> 6;
  const int wr = w >> 1, wc = w & 1;
  const int m0 = blockIdx.y*128, n0 = blockIdx.x*128;
  const int kbeg = blockIdx.z * KC, kend = kbeg + KC;
  const int l15 = lane & 15;
  const int g8 = (lane >> 4) << 3;

  f32x4 acc[4][4];
  #pragma unroll
  for (int i = 0; i < 4; ++i)
    #pragma unroll
    for (int j = 0; j < 4; ++j) acc[i][j] = 0.f;

  const char* Ab = (const char*)A;
  const char* Bb = (const char*)Bt;
  const int off  = t*16;
  const int srow = off >> 6;
  const int scolb = (((off >> 4) & 3) ^ ((srow >> 1) & 3)) << 4;

  const size_t arow0 = (size_t)(m0+srow)*K, arow1 = (size_t)(m0+srow+64)*K;
  const size_t brow0 = (size_t)(n0+srow)*K, brow1 = (size_t)(n0+srow+64)*K;

#define STAGE(buf, kk)  do {                                          \
    gload16(Ab + (arow0 + (kk))*2 + scolb, (char*)Asm[buf] + off);    \
    gload16(Ab + (arow1 + (kk))*2 + scolb, (char*)Asm[buf] + off + 4096); \
    gload16(Bb + (brow0 + (kk))*2 + scolb, (char*)Bsm[buf] + off);    \
    gload16(Bb + (brow1 + (kk))*2 + scolb, (char*)Bsm[buf] + off + 4096); \
  } while (0)

  STAGE(0, kbeg);
  int cur = 0;

  for (int k0 = kbeg; k0 < kend; k0 += 32) {
    if (k0 + 32 < kend) {
      STAGE(cur ^ 1, k0 + 32);
      asm volatile("s_waitcnt vmcnt(4)" ::: "memory");
    } else {
      asm volatile("s_waitcnt vmcnt(0)" ::: "memory");
    }
    __builtin_amdgcn_s_barrier();
    __builtin_amdgcn_sched_barrier(0);

    const bf16* Ac = Asm[cur];
    const bf16* Bc = Bsm[cur];
    short4v alo[4], ahi[4], blo[4], bhi[4];
    #pragma unroll
    for (int i = 0; i < 4; ++i) {
      const int arow = wr*64 + i*16 + l15;
      const int asw  = ((arow >> 1) & 3) << 4;
      const char* ap = (const char*)Ac + arow*64;
      alo[i] = *(const short4v*)(ap + (g8 ^ asw));
      ahi[i] = *(const short4v*)(ap + ((32 + g8) ^ asw));
      const int brow = wc*64 + i*16 + l15;
      const int bsw  = ((brow >> 1) & 3) << 4;
      const char* bp = (const char*)Bc + brow*64;
      blo[i] = *(const short4v*)(bp + (g8 ^ bsw));
      bhi[i] = *(const short4v*)(bp + ((32 + g8) ^ bsw));
    }
    #pragma unroll
    for (int i = 0; i < 4; ++i) {
      short8v a = CAT8(alo[i], ahi[i]);
      #pragma unroll
      for (int j = 0; j < 4; ++j) {
        short8v b = CAT8(blo[j], bhi[j]);
        acc[i][j] = MFMA16(a, b, acc[i][j]);
      }
    }
    __builtin_amdgcn_sched_barrier(0);
    __builtin_amdgcn_s_barrier();
    cur ^= 1;
  }
#undef STAGE

  #pragma unroll
  for (int i = 0; i < 4; ++i) {
    int row0 = m0 + wr*64 + i*16 + ((lane>>4)<<2);
    #pragma unroll
    for (int j = 0; j < 4; ++j) {
      int col = n0 + wc*64 + j*16 + l15;
      #pragma unroll
      for (int r = 0; r < 4; ++r)
        atomicAdd(&C[(size_t)(row0+r)*ldc + col], acc[i][j][r]);
    }
  }
}

// ---------------- V transpose: Vb [8][2048][64] -> Vt [8][64][2048] ----------------
__global__ __launch_bounds__(256) void k_vtrans(const bf16* __restrict__ Vb, bf16* __restrict__ Vt) {
  __shared__ bf16 ts[64][72];
  const int kv = blockIdx.y;
  const int s0 = blockIdx.x*64;
  const int t  = threadIdx.x;
  const bf16* src = Vb + ((size_t)kv*2048 + s0)*64;
  #pragma unroll
  for (int ii = 0; ii < 2; ++ii) {
    int idx = ii*256 + t;
    int s = idx >> 3, d8 = (idx & 7)*8;
    *(int4*)&ts[s][d8] = *(const int4*)(src + s*64 + d8);
  }
  __syncthreads();
  #pragma unroll
  for (int ii = 0; ii < 2; ++ii) {
    int idx = ii*256 + t;
    int d = idx >> 3, sB = (idx & 7)*8;
    short8v v;
    #pragma unroll
    for (int e = 0; e < 8; ++e) v[e] = __builtin_bit_cast(short, ts[sB+e][d]);
    *(short8v*)(Vt + (size_t)kv*64*2048 + (size_t)d*2048 + s0 + sB) = v;
  }
}

// ---------------- causal flash attention v3 (unchanged from R5-proven) ----------------
#define SCALE2 0.18033688011f   /* (1/sqrt(64)) * log2(e) */
__global__ __launch_bounds__(512) void k_attn(const bf16* __restrict__ Qb, const bf16* __restrict__ Kb,
                                              const bf16* __restrict__ Vt, bf16* __restrict__ attnb) {
  __shared__ bf16 Ksm[64][68];
  __shared__ bf16 Vsm[64][68];
  const int t = threadIdx.x, lane = t & 63, w = t >> 6;
  const int bid = blockIdx.x;
  const int h = bid & 31;
  const int qi = 15 - (bid >> 5);          // heavy blocks first
  const int qb0 = qi * 128;
  const int kvh = h >> 2;
  const int kb = (lane>>4)*4;
  const int l15 = lane & 15;

  const bf16* Qh = Qb + (size_t)h*2048*64;
  const bf16* Kh = Kb + (size_t)kvh*2048*64;
  const bf16* Vh = Vt + (size_t)kvh*64*2048;

  const int qrow = qb0 + w*16 + l15;
  short4v qlo[2], qhi[2];
  #pragma unroll
  for (int kk = 0; kk < 2; ++kk) {
    qlo[kk] = *(const short4v*)(Qh + (size_t)qrow*64 + kk*32 + kb);
    qhi[kk] = *(const short4v*)(Qh + (size_t)qrow*64 + kk*32 + 16 + kb);
  }

  float m_ = -3e38f, ls = 0.f;
  f32x4 o2[4];
  #pragma unroll
  for (int j = 0; j < 4; ++j) o2[j] = 0.f;

  const int srow = t >> 3;
  const int sc8  = (t & 7) * 8;

  const int nt = 2*qi + 2;
  for (int tt = 0; tt < nt; ++tt) {
    *(int4*)(&Ksm[srow][sc8]) = *(const int4*)(Kh + ((size_t)(tt*64 + srow))*64 + sc8);
    *(int4*)(&Vsm[srow][sc8]) = *(const int4*)(Vh + (size_t)srow*2048 + tt*64 + sc8);
    __syncthreads();

    f32x4 sAcc[4];
    #pragma unroll
    for (int j = 0; j < 4; ++j) sAcc[j] = 0.f;
    __builtin_amdgcn_s_setprio(1);
    #pragma unroll
    for (int kk = 0; kk < 2; ++kk) {
      short8v bq = CAT8(qlo[kk], qhi[kk]);
      #pragma unroll
      for (int j = 0; j < 4; ++j) {
        const bf16* kp = &Ksm[j*16 + l15][kk*32 + kb];
        short8v ak = CAT8(*(const short4v*)kp, *(const short4v*)(kp + 16));
        sAcc[j] = MFMA16(ak, bq, sAcc[j]);
      }
    }
    __builtin_amdgcn_s_setprio(0);

    float p[4][4];
    #pragma unroll
    for (int j = 0; j < 4; ++j)
      #pragma unroll
      for (int r = 0; r < 4; ++r) p[j][r] = sAcc[j][r]*SCALE2;
    if (tt*64 + 63 > qb0 + w*16) {
      #pragma unroll
      for (int j = 0; j < 4; ++j) {
        #pragma unroll
        for (int r = 0; r < 4; ++r)
          if (tt*64 + j*16 + kb + r > qrow) p[j][r] = -3e38f;
      }
    }

    float mx = p[0][0];
    #pragma unroll
    for (int j = 0; j < 4; ++j)
      #pragma unroll
      for (int r = 0; r < 4; ++r) mx = fmaxf(mx, p[j][r]);
    mx = fmaxf(mx, __shfl_xor(mx, 16));
    mx = fmaxf(mx, __shfl_xor(mx, 32));
    float mn = fmaxf(m_, mx);
    float alpha = exp2f(m_ - mn);
    m_ = mn;
    ls *= alpha;
    #pragma unroll
    for (int j = 0; j < 4; ++j) o2[j] *= alpha;

    float rs = 0.f;
    #pragma unroll
    for (int j = 0; j < 4; ++j)
      #pragma unroll
      for (int r = 0; r < 4; ++r) {
        float e = exp2f(p[j][r] - mn);
        p[j][r] = e;
        rs += e;
      }
    rs += __shfl_xor(rs, 16);
    rs += __shfl_xor(rs, 32);
    ls += rs;

    short8v pb[2];
    #pragma unroll
    for (int kk = 0; kk < 2; ++kk) {
      short8v v;
      v[0] = f2bs(p[2*kk][0]);   v[1] = f2bs(p[2*kk][1]);
      v[2] = f2bs(p[2*kk][2]);   v[3] = f2bs(p[2*kk][3]);
      v[4] = f2bs(p[2*kk+1][0]); v[5] = f2bs(p[2*kk+1][1]);
      v[6] = f2bs(p[2*kk+1][2]); v[7] = f2bs(p[2*kk+1][3]);
      pb[kk] = v;
    }

    __builtin_amdgcn_s_setprio(1);
    #pragma unroll
    for (int kk = 0; kk < 2; ++kk) {
      #pragma unroll
      for (int j = 0; j < 4; ++j) {
        const bf16* vp = &Vsm[j*16 + l15][kk*32 + kb];
        short8v av = CAT8(*(const short4v*)vp, *(const short4v*)(vp + 16));
        o2[j] = MFMA16(av, pb[kk], o2[j]);
      }
    }
    __builtin_amdgcn_s_setprio(0);
    __syncthreads();
  }

  float inv = 1.0f / ls;
  #pragma unroll
  for (int j = 0; j < 4; ++j)
    #pragma unroll
    for (int r = 0; r < 4; ++r)
      attnb[(size_t)qrow*2048 + h*64 + j*16 + kb + r] = __float2bfloat16(o2[j][r]*inv);
}

extern "C" void kernel_launch(void* const* d_in, const int* in_sizes, int n_in,
                              void* d_out, int out_size, void* d_ws, size_t ws_size,
                              hipStream_t stream) {
  const float* x    = (const float*)d_in[0];
  const float* cosb = (const float*)d_in[2];
  const float* sinb = (const float*)d_in[3];
  const float* Wq   = (const float*)d_in[4];
  const float* Wk   = (const float*)d_in[5];
  const float* Wv   = (const float*)d_in[6];
  const float* Wo   = (const float*)d_in[7];
  const float* qg   = (const float*)d_in[8];
  const float* kg   = (const float*)d_in[9];
  float* out = (float*)d_out;

  char* ws = (char*)d_ws;
  bf16*  xb    = (bf16*)(ws);                    // 8 MB  [2048][2048] (live through QKV GEMM)
  bf16*  WqT   = (bf16*)(ws + 8388608);          // 8 MB
  bf16*  WkT   = (bf16*)(ws + 16777216);         // 2 MB
  bf16*  WvT   = (bf16*)(ws + 18874368);         // 2 MB  (WqT..WvT contiguous: N=3072 B-panel)
  bf16*  WoT   = (bf16*)(ws + 20971520);         // 8 MB  (live until out-proj)
  bf16*  Qb    = (bf16*)(ws + 29360128);         // 8 MB  [32][2048][64]
  bf16*  Kb    = (bf16*)(ws + 37748736);         // 2 MB  [8][2048][64]
  bf16*  Vb    = (bf16*)(ws + 39845888);         // 2 MB  [8][2048][64]
  bf16*  Vt    = (bf16*)(ws + 41943040);         // 2 MB  [8][64][2048]
  bf16*  attnb = (bf16*)(ws);                    // 8 MB  (overlays xb, dead after QKV GEMM)

  hipMemsetAsync(out, 0, (size_t)out_size*4, stream);   // atomic target for out-proj

  k_cvt_x<<<4096, 256, 0, stream>>>(x, xb);
  k_transpose_cvt<<<dim3(32, 32), 256, 0, stream>>>(Wq, WqT, 2048, 2048);
  k_transpose_cvt<<<dim3(8, 32),  256, 0, stream>>>(Wk, WkT, 2048, 512);
  k_transpose_cvt<<<dim3(8, 32),  256, 0, stream>>>(Wv, WvT, 2048, 512);
  k_transpose_cvt<<<dim3(32, 32), 256, 0, stream>>>(Wo, WoT, 2048, 2048);

  // QKV projection + fused RMSNorm/RoPE epilogue (384 blocks, no split-K)
  k_gemm_qkv<<<dim3(24, 16), 256, 0, stream>>>(xb, WqT, cosb, sinb, qg, kg, Qb, Kb, Vb, 2048);
  k_vtrans<<<dim3(32, 8), 256, 0, stream>>>(Vb, Vt);
  k_attn<<<512, 512, 0, stream>>>(Qb, Kb, Vt, attnb);
  // output projection: R6-proven split-K x2 (512 blocks), atomicAdd into d_out
  k_gemm_out<<<dim3(16, 16, 2), 256, 0, stream>>>(attnb, WoT, out, 2048, 2048, 2048, 1024, 2048);
}

// Round 10
// 211.552 us; speedup vs baseline: 1.2191x; 1.0013x over previous
//
#include <hip/hip_runtime.h>
#include <hip/hip_bf16.h>
#include <stdint.h>

typedef __hip_bfloat16 bf16;
typedef __attribute__((ext_vector_type(4))) short short4v;
typedef __attribute__((ext_vector_type(8))) short short8v;
typedef __attribute__((ext_vector_type(4))) float f32x4;

#define CAT8(lo,hi) __builtin_shufflevector(lo, hi, 0,1,2,3,4,5,6,7)
#define MFMA16(a,b,c) __builtin_amdgcn_mfma_f32_16x16x32_bf16(a,b,c,0,0,0)

__device__ __forceinline__ void gload16(const void* g, void* l) {
  __builtin_amdgcn_global_load_lds((const __attribute__((address_space(1))) unsigned int*)g,
                                   (__attribute__((address_space(3))) unsigned int*)l, 16, 0, 0);
}

__device__ __forceinline__ short f2bs(float f) {
  return __builtin_bit_cast(short, __float2bfloat16(f));
}

// ---------------- convert x (f32 -> bf16), 4 elems/thread ----------------
__global__ __launch_bounds__(256) void k_cvt_x(const float* __restrict__ in, bf16* __restrict__ out) {
  int i = blockIdx.x*256 + threadIdx.x;
  float4 v = ((const float4*)in)[i];
  bf16* o = out + (size_t)i*4;
  o[0] = __float2bfloat16(v.x); o[1] = __float2bfloat16(v.y);
  o[2] = __float2bfloat16(v.z); o[3] = __float2bfloat16(v.w);
}

// ---------------- transpose-convert: W[K][N] f32 -> Wt[N][K] bf16 ----------------
__global__ __launch_bounds__(256) void k_transpose_cvt(const float* __restrict__ W, bf16* __restrict__ Wt,
                                                       int K, int N) {
  __shared__ float ts[64][65];
  int k0 = blockIdx.y*64, n0 = blockIdx.x*64;
  int t = threadIdx.x;
  #pragma unroll
  for (int ii = 0; ii < 16; ++ii) {
    int idx = ii*256 + t; int r = idx>>6, c = idx&63;
    ts[r][c] = W[(size_t)(k0+r)*N + n0 + c];
  }
  __syncthreads();
  #pragma unroll
  for (int ii = 0; ii < 16; ++ii) {
    int idx = ii*256 + t; int r = idx>>6, c = idx&63;   // r: n-row, c: k-col
    Wt[(size_t)(n0+r)*K + k0 + c] = __float2bfloat16(ts[c][r]);
  }
}

// ---------------- QKV GEMM, FUSED RMSNorm+RoPE epilogue, DEPTH-2 prefetch ----------------
// 128x128 tile, BK=32, 4 waves 2x2. Triple-buffered LDS: at step t stage tile t+2;
// gate vmcnt(8) (tiles t+1,t+2 in flight) -> each tile's loads get ~2 step-times
// to cover HBM/L2 latency. Tail drains 4 -> 0. Buffer staged at t was last read
// at t-1 (protected by end-of-step barrier).
__global__ __launch_bounds__(256) void k_gemm_qkv(const bf16* __restrict__ A, const bf16* __restrict__ Bt,
                                                  const float* __restrict__ cosb, const float* __restrict__ sinb,
                                                  const float* __restrict__ qg, const float* __restrict__ kg,
                                                  bf16* __restrict__ Qb, bf16* __restrict__ Kb,
                                                  bf16* __restrict__ Vb, int K) {
  __shared__ bf16 Asm[3][128*32];
  __shared__ bf16 Bsm[3][128*32];
  const int t = threadIdx.x;
  const int lane = t & 63, w = t >> 6;
  const int wr = w >> 1, wc = w & 1;
  const int m0 = blockIdx.y*128, n0 = blockIdx.x*128;
  const int l15 = lane & 15;
  const int g8 = (lane >> 4) << 3;

  f32x4 acc[4][4];
  #pragma unroll
  for (int i = 0; i < 4; ++i)
    #pragma unroll
    for (int j = 0; j < 4; ++j) acc[i][j] = 0.f;

  const char* Ab = (const char*)A;
  const char* Bb = (const char*)Bt;
  const int off  = t*16;
  const int srow = off >> 6;
  const int scolb = (((off >> 4) & 3) ^ ((srow >> 1) & 3)) << 4;

  const size_t arow0 = (size_t)(m0+srow)*K, arow1 = (size_t)(m0+srow+64)*K;
  const size_t brow0 = (size_t)(n0+srow)*K, brow1 = (size_t)(n0+srow+64)*K;

#define STAGE(buf, kk)  do {                                          \
    gload16(Ab + (arow0 + (kk))*2 + scolb, (char*)Asm[buf] + off);    \
    gload16(Ab + (arow1 + (kk))*2 + scolb, (char*)Asm[buf] + off + 4096); \
    gload16(Bb + (brow0 + (kk))*2 + scolb, (char*)Bsm[buf] + off);    \
    gload16(Bb + (brow1 + (kk))*2 + scolb, (char*)Bsm[buf] + off + 4096); \
  } while (0)

  const int nsteps = K >> 5;
  STAGE(0, 0);
  STAGE(1, 32);

  for (int it = 0; it < nsteps; ++it) {
    const int kf = (it + 2) << 5;
    if (kf < K) {
      STAGE((it + 2) % 3, kf);
      asm volatile("s_waitcnt vmcnt(8)" ::: "memory");
    } else if (it + 1 < nsteps) {
      asm volatile("s_waitcnt vmcnt(4)" ::: "memory");
    } else {
      asm volatile("s_waitcnt vmcnt(0)" ::: "memory");
    }
    __builtin_amdgcn_s_barrier();
    __builtin_amdgcn_sched_barrier(0);

    const bf16* Ac = Asm[it % 3];
    const bf16* Bc = Bsm[it % 3];
    short4v alo[4], ahi[4], blo[4], bhi[4];
    #pragma unroll
    for (int i = 0; i < 4; ++i) {
      const int arow = wr*64 + i*16 + l15;
      const int asw  = ((arow >> 1) & 3) << 4;
      const char* ap = (const char*)Ac + arow*64;
      alo[i] = *(const short4v*)(ap + (g8 ^ asw));
      ahi[i] = *(const short4v*)(ap + ((32 + g8) ^ asw));
      const int brow = wc*64 + i*16 + l15;
      const int bsw  = ((brow >> 1) & 3) << 4;
      const char* bp = (const char*)Bc + brow*64;
      blo[i] = *(const short4v*)(bp + (g8 ^ bsw));
      bhi[i] = *(const short4v*)(bp + ((32 + g8) ^ bsw));
    }
    #pragma unroll
    for (int i = 0; i < 4; ++i) {
      short8v a = CAT8(alo[i], ahi[i]);
      #pragma unroll
      for (int j = 0; j < 4; ++j) {
        short8v b = CAT8(blo[j], bhi[j]);
        acc[i][j] = MFMA16(a, b, acc[i][j]);
      }
    }
    __builtin_amdgcn_sched_barrier(0);
    __builtin_amdgcn_s_barrier();
  }
#undef STAGE

  // ---- fused epilogue: rmsnorm + rope (Q/K) or plain cvt (V) ----
  const int hh = (n0 + wc*64) >> 6;            // head id 0..47 (wave-uniform)
  float gam[4];
  if (hh < 40) {
    const float* gp = (hh < 32) ? qg : kg;
    #pragma unroll
    for (int j = 0; j < 4; ++j) gam[j] = gp[j*16 + l15];
  }
  #pragma unroll
  for (int i = 0; i < 4; ++i) {
    #pragma unroll
    for (int rr = 0; rr < 4; ++rr) {
      const int row = m0 + wr*64 + i*16 + ((lane>>4)<<2) + rr;   // absolute s
      float v0 = acc[i][0][rr], v1 = acc[i][1][rr], v2 = acc[i][2][rr], v3 = acc[i][3][rr];
      if (hh < 40) {
        float ss = v0*v0 + v1*v1 + v2*v2 + v3*v3;
        ss += __shfl_xor(ss, 1); ss += __shfl_xor(ss, 2);
        ss += __shfl_xor(ss, 4); ss += __shfl_xor(ss, 8);
        const float rms = rsqrtf(ss*(1.0f/64.0f) + 1e-6f);
        const float t0 = v0*rms*gam[0], t1 = v1*rms*gam[1];
        const float t2 = v2*rms*gam[2], t3 = v3*rms*gam[3];
        const float* cr = cosb + (size_t)row*64;
        const float* sr = sinb + (size_t)row*64;
        const float o0 = t0*cr[l15]      - t2*sr[l15];
        const float o1 = t1*cr[16+l15]   - t3*sr[16+l15];
        const float o2 = t2*cr[32+l15]   + t0*sr[32+l15];
        const float o3 = t3*cr[48+l15]   + t1*sr[48+l15];
        bf16* dst = (hh < 32) ? (Qb + ((size_t)hh*2048 + row)*64)
                              : (Kb + ((size_t)(hh-32)*2048 + row)*64);
        dst[l15]      = __float2bfloat16(o0);
        dst[16 + l15] = __float2bfloat16(o1);
        dst[32 + l15] = __float2bfloat16(o2);
        dst[48 + l15] = __float2bfloat16(o3);
      } else {
        bf16* dst = Vb + ((size_t)(hh-40)*2048 + row)*64;
        dst[l15]      = __float2bfloat16(v0);
        dst[16 + l15] = __float2bfloat16(v1);
        dst[32 + l15] = __float2bfloat16(v2);
        dst[48 + l15] = __float2bfloat16(v3);
      }
    }
  }
}

// ---------------- out-proj GEMM: split-K, DEPTH-2 prefetch (tri-buffer) ----------------
__global__ __launch_bounds__(256) void k_gemm_out(const bf16* __restrict__ A, const bf16* __restrict__ Bt,
                                                  float* __restrict__ C, int M, int N, int K,
                                                  int KC, int ldc) {
  __shared__ bf16 Asm[3][128*32];
  __shared__ bf16 Bsm[3][128*32];
  const int t = threadIdx.x;
  const int lane = t & 63, w = t >> 6;
  const int wr = w >> 1, wc = w & 1;
  const int m0 = blockIdx.y*128, n0 = blockIdx.x*128;
  const int kbeg = blockIdx.z * KC;
  const int l15 = lane & 15;
  const int g8 = (lane >> 4) << 3;

  f32x4 acc[4][4];
  #pragma unroll
  for (int i = 0; i < 4; ++i)
    #pragma unroll
    for (int j = 0; j < 4; ++j) acc[i][j] = 0.f;

  const char* Ab = (const char*)A;
  const char* Bb = (const char*)Bt;
  const int off  = t*16;
  const int srow = off >> 6;
  const int scolb = (((off >> 4) & 3) ^ ((srow >> 1) & 3)) << 4;

  const size_t arow0 = (size_t)(m0+srow)*K, arow1 = (size_t)(m0+srow+64)*K;
  const size_t brow0 = (size_t)(n0+srow)*K, brow1 = (size_t)(n0+srow+64)*K;

#define STAGE(buf, kk)  do {                                          \
    gload16(Ab + (arow0 + (kk))*2 + scolb, (char*)Asm[buf] + off);    \
    gload16(Ab + (arow1 + (kk))*2 + scolb, (char*)Asm[buf] + off + 4096); \
    gload16(Bb + (brow0 + (kk))*2 + scolb, (char*)Bsm[buf] + off);    \
    gload16(Bb + (brow1 + (kk))*2 + scolb, (char*)Bsm[buf] + off + 4096); \
  } while (0)

  const int nsteps = KC >> 5;
  STAGE(0, kbeg);
  STAGE(1, kbeg + 32);

  for (int it = 0; it < nsteps; ++it) {
    if (it + 2 < nsteps) {
      STAGE((it + 2) % 3, kbeg + ((it + 2) << 5));
      asm volatile("s_waitcnt vmcnt(8)" ::: "memory");
    } else if (it + 1 < nsteps) {
      asm volatile("s_waitcnt vmcnt(4)" ::: "memory");
    } else {
      asm volatile("s_waitcnt vmcnt(0)" ::: "memory");
    }
    __builtin_amdgcn_s_barrier();
    __builtin_amdgcn_sched_barrier(0);

    const bf16* Ac = Asm[it % 3];
    const bf16* Bc = Bsm[it % 3];
    short4v alo[4], ahi[4], blo[4], bhi[4];
    #pragma unroll
    for (int i = 0; i < 4; ++i) {
      const int arow = wr*64 + i*16 + l15;
      const int asw  = ((arow >> 1) & 3) << 4;
      const char* ap = (const char*)Ac + arow*64;
      alo[i] = *(const short4v*)(ap + (g8 ^ asw));
      ahi[i] = *(const short4v*)(ap + ((32 + g8) ^ asw));
      const int brow = wc*64 + i*16 + l15;
      const int bsw  = ((brow >> 1) & 3) << 4;
      const char* bp = (const char*)Bc + brow*64;
      blo[i] = *(const short4v*)(bp + (g8 ^ bsw));
      bhi[i] = *(const short4v*)(bp + ((32 + g8) ^ bsw));
    }
    #pragma unroll
    for (int i = 0; i < 4; ++i) {
      short8v a = CAT8(alo[i], ahi[i]);
      #pragma unroll
      for (int j = 0; j < 4; ++j) {
        short8v b = CAT8(blo[j], bhi[j]);
        acc[i][j] = MFMA16(a, b, acc[i][j]);
      }
    }
    __builtin_amdgcn_sched_barrier(0);
    __builtin_amdgcn_s_barrier();
  }
#undef STAGE

  #pragma unroll
  for (int i = 0; i < 4; ++i) {
    int row0 = m0 + wr*64 + i*16 + ((lane>>4)<<2);
    #pragma unroll
    for (int j = 0; j < 4; ++j) {
      int col = n0 + wc*64 + j*16 + l15;
      #pragma unroll
      for (int r = 0; r < 4; ++r)
        atomicAdd(&C[(size_t)(row0+r)*ldc + col], acc[i][j][r]);
    }
  }
}

// ---------------- V transpose: Vb [8][2048][64] -> Vt [8][64][2048] ----------------
__global__ __launch_bounds__(256) void k_vtrans(const bf16* __restrict__ Vb, bf16* __restrict__ Vt) {
  __shared__ bf16 ts[64][72];
  const int kv = blockIdx.y;
  const int s0 = blockIdx.x*64;
  const int t  = threadIdx.x;
  const bf16* src = Vb + ((size_t)kv*2048 + s0)*64;
  #pragma unroll
  for (int ii = 0; ii < 2; ++ii) {
    int idx = ii*256 + t;
    int s = idx >> 3, d8 = (idx & 7)*8;
    *(int4*)&ts[s][d8] = *(const int4*)(src + s*64 + d8);
  }
  __syncthreads();
  #pragma unroll
  for (int ii = 0; ii < 2; ++ii) {
    int idx = ii*256 + t;
    int d = idx >> 3, sB = (idx & 7)*8;
    short8v v;
    #pragma unroll
    for (int e = 0; e < 8; ++e) v[e] = __builtin_bit_cast(short, ts[sB+e][d]);
    *(short8v*)(Vt + (size_t)kv*64*2048 + (size_t)d*2048 + s0 + sB) = v;
  }
}

// ---------------- causal flash attention v3 (unchanged) ----------------
#define SCALE2 0.18033688011f   /* (1/sqrt(64)) * log2(e) */
__global__ __launch_bounds__(512) void k_attn(const bf16* __restrict__ Qb, const bf16* __restrict__ Kb,
                                              const bf16* __restrict__ Vt, bf16* __restrict__ attnb) {
  __shared__ bf16 Ksm[64][68];
  __shared__ bf16 Vsm[64][68];
  const int t = threadIdx.x, lane = t & 63, w = t >> 6;
  const int bid = blockIdx.x;
  const int h = bid & 31;
  const int qi = 15 - (bid >> 5);          // heavy blocks first
  const int qb0 = qi * 128;
  const int kvh = h >> 2;
  const int kb = (lane>>4)*4;
  const int l15 = lane & 15;

  const bf16* Qh = Qb + (size_t)h*2048*64;
  const bf16* Kh = Kb + (size_t)kvh*2048*64;
  const bf16* Vh = Vt + (size_t)kvh*64*2048;

  const int qrow = qb0 + w*16 + l15;
  short4v qlo[2], qhi[2];
  #pragma unroll
  for (int kk = 0; kk < 2; ++kk) {
    qlo[kk] = *(const short4v*)(Qh + (size_t)qrow*64 + kk*32 + kb);
    qhi[kk] = *(const short4v*)(Qh + (size_t)qrow*64 + kk*32 + 16 + kb);
  }

  float m_ = -3e38f, ls = 0.f;
  f32x4 o2[4];
  #pragma unroll
  for (int j = 0; j < 4; ++j) o2[j] = 0.f;

  const int srow = t >> 3;
  const int sc8  = (t & 7) * 8;

  const int nt = 2*qi + 2;
  for (int tt = 0; tt < nt; ++tt) {
    *(int4*)(&Ksm[srow][sc8]) = *(const int4*)(Kh + ((size_t)(tt*64 + srow))*64 + sc8);
    *(int4*)(&Vsm[srow][sc8]) = *(const int4*)(Vh + (size_t)srow*2048 + tt*64 + sc8);
    __syncthreads();

    f32x4 sAcc[4];
    #pragma unroll
    for (int j = 0; j < 4; ++j) sAcc[j] = 0.f;
    __builtin_amdgcn_s_setprio(1);
    #pragma unroll
    for (int kk = 0; kk < 2; ++kk) {
      short8v bq = CAT8(qlo[kk], qhi[kk]);
      #pragma unroll
      for (int j = 0; j < 4; ++j) {
        const bf16* kp = &Ksm[j*16 + l15][kk*32 + kb];
        short8v ak = CAT8(*(const short4v*)kp, *(const short4v*)(kp + 16));
        sAcc[j] = MFMA16(ak, bq, sAcc[j]);
      }
    }
    __builtin_amdgcn_s_setprio(0);

    float p[4][4];
    #pragma unroll
    for (int j = 0; j < 4; ++j)
      #pragma unroll
      for (int r = 0; r < 4; ++r) p[j][r] = sAcc[j][r]*SCALE2;
    if (tt*64 + 63 > qb0 + w*16) {
      #pragma unroll
      for (int j = 0; j < 4; ++j) {
        #pragma unroll
        for (int r = 0; r < 4; ++r)
          if (tt*64 + j*16 + kb + r > qrow) p[j][r] = -3e38f;
      }
    }

    float mx = p[0][0];
    #pragma unroll
    for (int j = 0; j < 4; ++j)
      #pragma unroll
      for (int r = 0; r < 4; ++r) mx = fmaxf(mx, p[j][r]);
    mx = fmaxf(mx, __shfl_xor(mx, 16));
    mx = fmaxf(mx, __shfl_xor(mx, 32));
    float mn = fmaxf(m_, mx);
    float alpha = exp2f(m_ - mn);
    m_ = mn;
    ls *= alpha;
    #pragma unroll
    for (int j = 0; j < 4; ++j) o2[j] *= alpha;

    float rs = 0.f;
    #pragma unroll
    for (int j = 0; j < 4; ++j)
      #pragma unroll
      for (int r = 0; r < 4; ++r) {
        float e = exp2f(p[j][r] - mn);
        p[j][r] = e;
        rs += e;
      }
    rs += __shfl_xor(rs, 16);
    rs += __shfl_xor(rs, 32);
    ls += rs;

    short8v pb[2];
    #pragma unroll
    for (int kk = 0; kk < 2; ++kk) {
      short8v v;
      v[0] = f2bs(p[2*kk][0]);   v[1] = f2bs(p[2*kk][1]);
      v[2] = f2bs(p[2*kk][2]);   v[3] = f2bs(p[2*kk][3]);
      v[4] = f2bs(p[2*kk+1][0]); v[5] = f2bs(p[2*kk+1][1]);
      v[6] = f2bs(p[2*kk+1][2]); v[7] = f2bs(p[2*kk+1][3]);
      pb[kk] = v;
    }

    __builtin_amdgcn_s_setprio(1);
    #pragma unroll
    for (int kk = 0; kk < 2; ++kk) {
      #pragma unroll
      for (int j = 0; j < 4; ++j) {
        const bf16* vp = &Vsm[j*16 + l15][kk*32 + kb];
        short8v av = CAT8(*(const short4v*)vp, *(const short4v*)(vp + 16));
        o2[j] = MFMA16(av, pb[kk], o2[j]);
      }
    }
    __builtin_amdgcn_s_setprio(0);
    __syncthreads();
  }

  float inv = 1.0f / ls;
  #pragma unroll
  for (int j = 0; j < 4; ++j)
    #pragma unroll
    for (int r = 0; r < 4; ++r)
      attnb[(size_t)qrow*2048 + h*64 + j*16 + kb + r] = __float2bfloat16(o2[j][r]*inv);
}

extern "C" void kernel_launch(void* const* d_in, const int* in_sizes, int n_in,
                              void* d_out, int out_size, void* d_ws, size_t ws_size,
                              hipStream_t stream) {
  const float* x    = (const float*)d_in[0];
  const float* cosb = (const float*)d_in[2];
  const float* sinb = (const float*)d_in[3];
  const float* Wq   = (const float*)d_in[4];
  const float* Wk   = (const float*)d_in[5];
  const float* Wv   = (const float*)d_in[6];
  const float* Wo   = (const float*)d_in[7];
  const float* qg   = (const float*)d_in[8];
  const float* kg   = (const float*)d_in[9];
  float* out = (float*)d_out;

  char* ws = (char*)d_ws;
  bf16*  xb    = (bf16*)(ws);                    // 8 MB  [2048][2048] (live through QKV GEMM)
  bf16*  WqT   = (bf16*)(ws + 8388608);          // 8 MB
  bf16*  WkT   = (bf16*)(ws + 16777216);         // 2 MB
  bf16*  WvT   = (bf16*)(ws + 18874368);         // 2 MB  (WqT..WvT contiguous: N=3072 B-panel)
  bf16*  WoT   = (bf16*)(ws + 20971520);         // 8 MB  (live until out-proj)
  bf16*  Qb    = (bf16*)(ws + 29360128);         // 8 MB  [32][2048][64]
  bf16*  Kb    = (bf16*)(ws + 37748736);         // 2 MB  [8][2048][64]
  bf16*  Vb    = (bf16*)(ws + 39845888);         // 2 MB  [8][2048][64]
  bf16*  Vt    = (bf16*)(ws + 41943040);         // 2 MB  [8][64][2048]
  bf16*  attnb = (bf16*)(ws);                    // 8 MB  (overlays xb, dead after QKV GEMM)

  hipMemsetAsync(out, 0, (size_t)out_size*4, stream);   // atomic target for out-proj

  k_cvt_x<<<4096, 256, 0, stream>>>(x, xb);
  k_transpose_cvt<<<dim3(32, 32), 256, 0, stream>>>(Wq, WqT, 2048, 2048);
  k_transpose_cvt<<<dim3(8, 32),  256, 0, stream>>>(Wk, WkT, 2048, 512);
  k_transpose_cvt<<<dim3(8, 32),  256, 0, stream>>>(Wv, WvT, 2048, 512);
  k_transpose_cvt<<<dim3(32, 32), 256, 0, stream>>>(Wo, WoT, 2048, 2048);

  // QKV projection + fused RMSNorm/RoPE epilogue (384 blocks, no split-K)
  k_gemm_qkv<<<dim3(24, 16), 256, 0, stream>>>(xb, WqT, cosb, sinb, qg, kg, Qb, Kb, Vb, 2048);
  k_vtrans<<<dim3(32, 8), 256, 0, stream>>>(Vb, Vt);
  k_attn<<<512, 512, 0, stream>>>(Qb, Kb, Vt, attnb);
  // output projection: split-K x2 (512 blocks), atomicAdd into d_out
  k_gemm_out<<<dim3(16, 16, 2), 256, 0, stream>>>(attnb, WoT, out, 2048, 2048, 2048, 1024, 2048);
}

// Round 11
// 197.656 us; speedup vs baseline: 1.3048x; 1.0703x over previous
//
#include <hip/hip_runtime.h>
#include <hip/hip_bf16.h>
#include <stdint.h>

typedef __hip_bfloat16 bf16;
typedef __attribute__((ext_vector_type(4))) short short4v;
typedef __attribute__((ext_vector_type(8))) short short8v;
typedef __attribute__((ext_vector_type(4))) float f32x4;

#define CAT8(lo,hi) __builtin_shufflevector(lo, hi, 0,1,2,3,4,5,6,7)
#define MFMA16(a,b,c) __builtin_amdgcn_mfma_f32_16x16x32_bf16(a,b,c,0,0,0)

__device__ __forceinline__ void gload16(const void* g, void* l) {
  __builtin_amdgcn_global_load_lds((const __attribute__((address_space(1))) unsigned int*)g,
                                   (__attribute__((address_space(3))) unsigned int*)l, 16, 0, 0);
}

__device__ __forceinline__ short f2bs(float f) {
  return __builtin_bit_cast(short, __float2bfloat16(f));
}

// ---------------- convert x (f32 -> bf16), 4 elems/thread ----------------
__global__ __launch_bounds__(256) void k_cvt_x(const float* __restrict__ in, bf16* __restrict__ out) {
  int i = blockIdx.x*256 + threadIdx.x;
  float4 v = ((const float4*)in)[i];
  bf16* o = out + (size_t)i*4;
  o[0] = __float2bfloat16(v.x); o[1] = __float2bfloat16(v.y);
  o[2] = __float2bfloat16(v.z); o[3] = __float2bfloat16(v.w);
}

// ---------------- transpose-convert: W[K][N] f32 -> Wt[N][K] bf16 ----------------
__global__ __launch_bounds__(256) void k_transpose_cvt(const float* __restrict__ W, bf16* __restrict__ Wt,
                                                       int K, int N) {
  __shared__ float ts[64][65];
  int k0 = blockIdx.y*64, n0 = blockIdx.x*64;
  int t = threadIdx.x;
  #pragma unroll
  for (int ii = 0; ii < 16; ++ii) {
    int idx = ii*256 + t; int r = idx>>6, c = idx&63;
    ts[r][c] = W[(size_t)(k0+r)*N + n0 + c];
  }
  __syncthreads();
  #pragma unroll
  for (int ii = 0; ii < 16; ++ii) {
    int idx = ii*256 + t; int r = idx>>6, c = idx&63;   // r: n-row, c: k-col
    Wt[(size_t)(n0+r)*K + k0 + c] = __float2bfloat16(ts[c][r]);
  }
}

// ---------------- QKV GEMM, FUSED RMSNorm+RoPE epilogue, depth-2 prefetch (frozen R10) ----------------
__global__ __launch_bounds__(256) void k_gemm_qkv(const bf16* __restrict__ A, const bf16* __restrict__ Bt,
                                                  const float* __restrict__ cosb, const float* __restrict__ sinb,
                                                  const float* __restrict__ qg, const float* __restrict__ kg,
                                                  bf16* __restrict__ Qb, bf16* __restrict__ Kb,
                                                  bf16* __restrict__ Vb, int K) {
  __shared__ bf16 Asm[3][128*32];
  __shared__ bf16 Bsm[3][128*32];
  const int t = threadIdx.x;
  const int lane = t & 63, w = t >> 6;
  const int wr = w >> 1, wc = w & 1;
  const int m0 = blockIdx.y*128, n0 = blockIdx.x*128;
  const int l15 = lane & 15;
  const int g8 = (lane >> 4) << 3;

  f32x4 acc[4][4];
  #pragma unroll
  for (int i = 0; i < 4; ++i)
    #pragma unroll
    for (int j = 0; j < 4; ++j) acc[i][j] = 0.f;

  const char* Ab = (const char*)A;
  const char* Bb = (const char*)Bt;
  const int off  = t*16;
  const int srow = off >> 6;
  const int scolb = (((off >> 4) & 3) ^ ((srow >> 1) & 3)) << 4;

  const size_t arow0 = (size_t)(m0+srow)*K, arow1 = (size_t)(m0+srow+64)*K;
  const size_t brow0 = (size_t)(n0+srow)*K, brow1 = (size_t)(n0+srow+64)*K;

#define STAGE(buf, kk)  do {                                          \
    gload16(Ab + (arow0 + (kk))*2 + scolb, (char*)Asm[buf] + off);    \
    gload16(Ab + (arow1 + (kk))*2 + scolb, (char*)Asm[buf] + off + 4096); \
    gload16(Bb + (brow0 + (kk))*2 + scolb, (char*)Bsm[buf] + off);    \
    gload16(Bb + (brow1 + (kk))*2 + scolb, (char*)Bsm[buf] + off + 4096); \
  } while (0)

  const int nsteps = K >> 5;
  STAGE(0, 0);
  STAGE(1, 32);

  for (int it = 0; it < nsteps; ++it) {
    const int kf = (it + 2) << 5;
    if (kf < K) {
      STAGE((it + 2) % 3, kf);
      asm volatile("s_waitcnt vmcnt(8)" ::: "memory");
    } else if (it + 1 < nsteps) {
      asm volatile("s_waitcnt vmcnt(4)" ::: "memory");
    } else {
      asm volatile("s_waitcnt vmcnt(0)" ::: "memory");
    }
    __builtin_amdgcn_s_barrier();
    __builtin_amdgcn_sched_barrier(0);

    const bf16* Ac = Asm[it % 3];
    const bf16* Bc = Bsm[it % 3];
    short4v alo[4], ahi[4], blo[4], bhi[4];
    #pragma unroll
    for (int i = 0; i < 4; ++i) {
      const int arow = wr*64 + i*16 + l15;
      const int asw  = ((arow >> 1) & 3) << 4;
      const char* ap = (const char*)Ac + arow*64;
      alo[i] = *(const short4v*)(ap + (g8 ^ asw));
      ahi[i] = *(const short4v*)(ap + ((32 + g8) ^ asw));
      const int brow = wc*64 + i*16 + l15;
      const int bsw  = ((brow >> 1) & 3) << 4;
      const char* bp = (const char*)Bc + brow*64;
      blo[i] = *(const short4v*)(bp + (g8 ^ bsw));
      bhi[i] = *(const short4v*)(bp + ((32 + g8) ^ bsw));
    }
    #pragma unroll
    for (int i = 0; i < 4; ++i) {
      short8v a = CAT8(alo[i], ahi[i]);
      #pragma unroll
      for (int j = 0; j < 4; ++j) {
        short8v b = CAT8(blo[j], bhi[j]);
        acc[i][j] = MFMA16(a, b, acc[i][j]);
      }
    }
    __builtin_amdgcn_sched_barrier(0);
    __builtin_amdgcn_s_barrier();
  }
#undef STAGE

  // ---- fused epilogue: rmsnorm + rope (Q/K) or plain cvt (V) ----
  const int hh = (n0 + wc*64) >> 6;            // head id 0..47 (wave-uniform)
  float gam[4];
  if (hh < 40) {
    const float* gp = (hh < 32) ? qg : kg;
    #pragma unroll
    for (int j = 0; j < 4; ++j) gam[j] = gp[j*16 + l15];
  }
  #pragma unroll
  for (int i = 0; i < 4; ++i) {
    #pragma unroll
    for (int rr = 0; rr < 4; ++rr) {
      const int row = m0 + wr*64 + i*16 + ((lane>>4)<<2) + rr;   // absolute s
      float v0 = acc[i][0][rr], v1 = acc[i][1][rr], v2 = acc[i][2][rr], v3 = acc[i][3][rr];
      if (hh < 40) {
        float ss = v0*v0 + v1*v1 + v2*v2 + v3*v3;
        ss += __shfl_xor(ss, 1); ss += __shfl_xor(ss, 2);
        ss += __shfl_xor(ss, 4); ss += __shfl_xor(ss, 8);
        const float rms = rsqrtf(ss*(1.0f/64.0f) + 1e-6f);
        const float t0 = v0*rms*gam[0], t1 = v1*rms*gam[1];
        const float t2 = v2*rms*gam[2], t3 = v3*rms*gam[3];
        const float* cr = cosb + (size_t)row*64;
        const float* sr = sinb + (size_t)row*64;
        const float o0 = t0*cr[l15]      - t2*sr[l15];
        const float o1 = t1*cr[16+l15]   - t3*sr[16+l15];
        const float o2 = t2*cr[32+l15]   + t0*sr[32+l15];
        const float o3 = t3*cr[48+l15]   + t1*sr[48+l15];
        bf16* dst = (hh < 32) ? (Qb + ((size_t)hh*2048 + row)*64)
                              : (Kb + ((size_t)(hh-32)*2048 + row)*64);
        dst[l15]      = __float2bfloat16(o0);
        dst[16 + l15] = __float2bfloat16(o1);
        dst[32 + l15] = __float2bfloat16(o2);
        dst[48 + l15] = __float2bfloat16(o3);
      } else {
        bf16* dst = Vb + ((size_t)(hh-40)*2048 + row)*64;
        dst[l15]      = __float2bfloat16(v0);
        dst[16 + l15] = __float2bfloat16(v1);
        dst[32 + l15] = __float2bfloat16(v2);
        dst[48 + l15] = __float2bfloat16(v3);
      }
    }
  }
}

// ---------------- out-proj GEMM: NO split-K, direct f32 store, depth-2 prefetch ----------------
__global__ __launch_bounds__(256) void k_gemm_out(const bf16* __restrict__ A, const bf16* __restrict__ Bt,
                                                  float* __restrict__ C, int M, int N, int K, int ldc) {
  __shared__ bf16 Asm[3][128*32];
  __shared__ bf16 Bsm[3][128*32];
  const int t = threadIdx.x;
  const int lane = t & 63, w = t >> 6;
  const int wr = w >> 1, wc = w & 1;
  const int m0 = blockIdx.y*128, n0 = blockIdx.x*128;
  const int l15 = lane & 15;
  const int g8 = (lane >> 4) << 3;

  f32x4 acc[4][4];
  #pragma unroll
  for (int i = 0; i < 4; ++i)
    #pragma unroll
    for (int j = 0; j < 4; ++j) acc[i][j] = 0.f;

  const char* Ab = (const char*)A;
  const char* Bb = (const char*)Bt;
  const int off  = t*16;
  const int srow = off >> 6;
  const int scolb = (((off >> 4) & 3) ^ ((srow >> 1) & 3)) << 4;

  const size_t arow0 = (size_t)(m0+srow)*K, arow1 = (size_t)(m0+srow+64)*K;
  const size_t brow0 = (size_t)(n0+srow)*K, brow1 = (size_t)(n0+srow+64)*K;

#define STAGE(buf, kk)  do {                                          \
    gload16(Ab + (arow0 + (kk))*2 + scolb, (char*)Asm[buf] + off);    \
    gload16(Ab + (arow1 + (kk))*2 + scolb, (char*)Asm[buf] + off + 4096); \
    gload16(Bb + (brow0 + (kk))*2 + scolb, (char*)Bsm[buf] + off);    \
    gload16(Bb + (brow1 + (kk))*2 + scolb, (char*)Bsm[buf] + off + 4096); \
  } while (0)

  const int nsteps = K >> 5;
  STAGE(0, 0);
  STAGE(1, 32);

  for (int it = 0; it < nsteps; ++it) {
    if (it + 2 < nsteps) {
      STAGE((it + 2) % 3, (it + 2) << 5);
      asm volatile("s_waitcnt vmcnt(8)" ::: "memory");
    } else if (it + 1 < nsteps) {
      asm volatile("s_waitcnt vmcnt(4)" ::: "memory");
    } else {
      asm volatile("s_waitcnt vmcnt(0)" ::: "memory");
    }
    __builtin_amdgcn_s_barrier();
    __builtin_amdgcn_sched_barrier(0);

    const bf16* Ac = Asm[it % 3];
    const bf16* Bc = Bsm[it % 3];
    short4v alo[4], ahi[4], blo[4], bhi[4];
    #pragma unroll
    for (int i = 0; i < 4; ++i) {
      const int arow = wr*64 + i*16 + l15;
      const int asw  = ((arow >> 1) & 3) << 4;
      const char* ap = (const char*)Ac + arow*64;
      alo[i] = *(const short4v*)(ap + (g8 ^ asw));
      ahi[i] = *(const short4v*)(ap + ((32 + g8) ^ asw));
      const int brow = wc*64 + i*16 + l15;
      const int bsw  = ((brow >> 1) & 3) << 4;
      const char* bp = (const char*)Bc + brow*64;
      blo[i] = *(const short4v*)(bp + (g8 ^ bsw));
      bhi[i] = *(const short4v*)(bp + ((32 + g8) ^ bsw));
    }
    #pragma unroll
    for (int i = 0; i < 4; ++i) {
      short8v a = CAT8(alo[i], ahi[i]);
      #pragma unroll
      for (int j = 0; j < 4; ++j) {
        short8v b = CAT8(blo[j], bhi[j]);
        acc[i][j] = MFMA16(a, b, acc[i][j]);
      }
    }
    __builtin_amdgcn_sched_barrier(0);
    __builtin_amdgcn_s_barrier();
  }
#undef STAGE

  #pragma unroll
  for (int i = 0; i < 4; ++i) {
    int row0 = m0 + wr*64 + i*16 + ((lane>>4)<<2);
    #pragma unroll
    for (int j = 0; j < 4; ++j) {
      int col = n0 + wc*64 + j*16 + l15;
      #pragma unroll
      for (int r = 0; r < 4; ++r)
        C[(size_t)(row0+r)*ldc + col] = acc[i][j][r];
    }
  }
}

// ---------------- V transpose: Vb [8][2048][64] -> Vt [8][64][2048] ----------------
__global__ __launch_bounds__(256) void k_vtrans(const bf16* __restrict__ Vb, bf16* __restrict__ Vt) {
  __shared__ bf16 ts[64][72];
  const int kv = blockIdx.y;
  const int s0 = blockIdx.x*64;
  const int t  = threadIdx.x;
  const bf16* src = Vb + ((size_t)kv*2048 + s0)*64;
  #pragma unroll
  for (int ii = 0; ii < 2; ++ii) {
    int idx = ii*256 + t;
    int s = idx >> 3, d8 = (idx & 7)*8;
    *(int4*)&ts[s][d8] = *(const int4*)(src + s*64 + d8);
  }
  __syncthreads();
  #pragma unroll
  for (int ii = 0; ii < 2; ++ii) {
    int idx = ii*256 + t;
    int d = idx >> 3, sB = (idx & 7)*8;
    short8v v;
    #pragma unroll
    for (int e = 0; e < 8; ++e) v[e] = __builtin_bit_cast(short, ts[sB+e][d]);
    *(short8v*)(Vt + (size_t)kv*64*2048 + (size_t)d*2048 + s0 + sB) = v;
  }
}

// ---------------- causal flash attention v4: KVBLK=128 ----------------
// Swapped-operand structure (R5-proven) with 128-wide KV tiles: 32 MFMA per
// barrier pair, half the barriers/staging per kv position. PV identity extends:
// pb[kk] = {p[2kk][0..3], p[2kk+1][0..3]}, kk=0..3. Only diagonal tile masks.
#define SCALE2 0.18033688011f   /* (1/sqrt(64)) * log2(e) */
__global__ __launch_bounds__(512) void k_attn(const bf16* __restrict__ Qb, const bf16* __restrict__ Kb,
                                              const bf16* __restrict__ Vt, bf16* __restrict__ attnb) {
  __shared__ bf16 Ksm[128][68];
  __shared__ bf16 Vsm[64][132];
  const int t = threadIdx.x, lane = t & 63, w = t >> 6;
  const int bid = blockIdx.x;
  const int h = bid & 31;
  const int qi = 15 - (bid >> 5);          // heavy blocks first
  const int qb0 = qi * 128;
  const int kvh = h >> 2;
  const int kb = (lane>>4)*4;
  const int l15 = lane & 15;

  const bf16* Qh = Qb + (size_t)h*2048*64;
  const bf16* Kh = Kb + (size_t)kvh*2048*64;
  const bf16* Vh = Vt + (size_t)kvh*64*2048;

  const int qrow = qb0 + w*16 + l15;       // this lane's q-row (replicated x4 groups)
  short4v qlo[2], qhi[2];
  #pragma unroll
  for (int kk = 0; kk < 2; ++kk) {
    qlo[kk] = *(const short4v*)(Qh + (size_t)qrow*64 + kk*32 + kb);
    qhi[kk] = *(const short4v*)(Qh + (size_t)qrow*64 + kk*32 + 16 + kb);
  }

  float m_ = -3e38f, ls = 0.f;
  f32x4 o2[4];
  #pragma unroll
  for (int j = 0; j < 4; ++j) o2[j] = 0.f;

  const int nt = qi + 1;
  for (int tt = 0; tt < nt; ++tt) {
    // stage K tile [128 kv][64 d] and V^T tile [64 d][128 s], 512 threads
    #pragma unroll
    for (int ii = 0; ii < 2; ++ii) {
      int idx = ii*512 + t;
      int kr = idx >> 3, kc = (idx & 7)*8;
      *(int4*)(&Ksm[kr][kc]) = *(const int4*)(Kh + ((size_t)(tt*128 + kr))*64 + kc);
      int vr = idx >> 4, vc = (idx & 15)*8;
      *(int4*)(&Vsm[vr][vc]) = *(const int4*)(Vh + (size_t)vr*2048 + tt*128 + vc);
    }
    __syncthreads();

    // S^T = K Q^T -> sAcc[j]: kv-block j (0..7), q = l15
    f32x4 sAcc[8];
    #pragma unroll
    for (int j = 0; j < 8; ++j) sAcc[j] = 0.f;
    __builtin_amdgcn_s_setprio(1);
    #pragma unroll
    for (int kk = 0; kk < 2; ++kk) {
      short8v bq = CAT8(qlo[kk], qhi[kk]);
      #pragma unroll
      for (int j = 0; j < 8; ++j) {
        const bf16* kp = &Ksm[j*16 + l15][kk*32 + kb];
        short8v ak = CAT8(*(const short4v*)kp, *(const short4v*)(kp + 16));
        sAcc[j] = MFMA16(ak, bq, sAcc[j]);
      }
    }
    __builtin_amdgcn_s_setprio(0);

    float p[8][4];
    #pragma unroll
    for (int j = 0; j < 8; ++j)
      #pragma unroll
      for (int r = 0; r < 4; ++r) p[j][r] = sAcc[j][r]*SCALE2;
    if (tt == nt - 1) {                      // diagonal tile: apply causal mask
      #pragma unroll
      for (int j = 0; j < 8; ++j) {
        #pragma unroll
        for (int r = 0; r < 4; ++r)
          if (tt*128 + j*16 + kb + r > qrow) p[j][r] = -3e38f;
      }
    }

    float mx = p[0][0];
    #pragma unroll
    for (int j = 0; j < 8; ++j)
      #pragma unroll
      for (int r = 0; r < 4; ++r) mx = fmaxf(mx, p[j][r]);
    mx = fmaxf(mx, __shfl_xor(mx, 16));
    mx = fmaxf(mx, __shfl_xor(mx, 32));
    float mn = fmaxf(m_, mx);
    float alpha = exp2f(m_ - mn);
    m_ = mn;
    ls *= alpha;
    #pragma unroll
    for (int j = 0; j < 4; ++j) o2[j] *= alpha;

    float rs = 0.f;
    #pragma unroll
    for (int j = 0; j < 8; ++j)
      #pragma unroll
      for (int r = 0; r < 4; ++r) {
        float e = exp2f(p[j][r] - mn);
        p[j][r] = e;
        rs += e;
      }
    rs += __shfl_xor(rs, 16);
    rs += __shfl_xor(rs, 32);
    ls += rs;

    // pack P into PV B-fragments: chunk kk = m-blocks {2kk, 2kk+1}, kk=0..3
    short8v pb[4];
    #pragma unroll
    for (int kk = 0; kk < 4; ++kk) {
      short8v v;
      v[0] = f2bs(p[2*kk][0]);   v[1] = f2bs(p[2*kk][1]);
      v[2] = f2bs(p[2*kk][2]);   v[3] = f2bs(p[2*kk][3]);
      v[4] = f2bs(p[2*kk+1][0]); v[5] = f2bs(p[2*kk+1][1]);
      v[6] = f2bs(p[2*kk+1][2]); v[7] = f2bs(p[2*kk+1][3]);
      pb[kk] = v;
    }

    // O^T += V^T P -> o2[j]: d-block j, q = l15
    __builtin_amdgcn_s_setprio(1);
    #pragma unroll
    for (int kk = 0; kk < 4; ++kk) {
      #pragma unroll
      for (int j = 0; j < 4; ++j) {
        const bf16* vp = &Vsm[j*16 + l15][kk*32 + kb];
        short8v av = CAT8(*(const short4v*)vp, *(const short4v*)(vp + 16));
        o2[j] = MFMA16(av, pb[kk], o2[j]);
      }
    }
    __builtin_amdgcn_s_setprio(0);
    __syncthreads();
  }

  float inv = 1.0f / ls;
  #pragma unroll
  for (int j = 0; j < 4; ++j)
    #pragma unroll
    for (int r = 0; r < 4; ++r)
      attnb[(size_t)qrow*2048 + h*64 + j*16 + kb + r] = __float2bfloat16(o2[j][r]*inv);
}

extern "C" void kernel_launch(void* const* d_in, const int* in_sizes, int n_in,
                              void* d_out, int out_size, void* d_ws, size_t ws_size,
                              hipStream_t stream) {
  const float* x    = (const float*)d_in[0];
  const float* cosb = (const float*)d_in[2];
  const float* sinb = (const float*)d_in[3];
  const float* Wq   = (const float*)d_in[4];
  const float* Wk   = (const float*)d_in[5];
  const float* Wv   = (const float*)d_in[6];
  const float* Wo   = (const float*)d_in[7];
  const float* qg   = (const float*)d_in[8];
  const float* kg   = (const float*)d_in[9];
  float* out = (float*)d_out;

  char* ws = (char*)d_ws;
  bf16*  xb    = (bf16*)(ws);                    // 8 MB  [2048][2048] (live through QKV GEMM)
  bf16*  WqT   = (bf16*)(ws + 8388608);          // 8 MB
  bf16*  WkT   = (bf16*)(ws + 16777216);         // 2 MB
  bf16*  WvT   = (bf16*)(ws + 18874368);         // 2 MB  (WqT..WvT contiguous: N=3072 B-panel)
  bf16*  WoT   = (bf16*)(ws + 20971520);         // 8 MB  (live until out-proj)
  bf16*  Qb    = (bf16*)(ws + 29360128);         // 8 MB  [32][2048][64]
  bf16*  Kb    = (bf16*)(ws + 37748736);         // 2 MB  [8][2048][64]
  bf16*  Vb    = (bf16*)(ws + 39845888);         // 2 MB  [8][2048][64]
  bf16*  Vt    = (bf16*)(ws + 41943040);         // 2 MB  [8][64][2048]
  bf16*  attnb = (bf16*)(ws);                    // 8 MB  (overlays xb, dead after QKV GEMM)

  k_cvt_x<<<4096, 256, 0, stream>>>(x, xb);
  k_transpose_cvt<<<dim3(32, 32), 256, 0, stream>>>(Wq, WqT, 2048, 2048);
  k_transpose_cvt<<<dim3(8, 32),  256, 0, stream>>>(Wk, WkT, 2048, 512);
  k_transpose_cvt<<<dim3(8, 32),  256, 0, stream>>>(Wv, WvT, 2048, 512);
  k_transpose_cvt<<<dim3(32, 32), 256, 0, stream>>>(Wo, WoT, 2048, 2048);

  // QKV projection + fused RMSNorm/RoPE epilogue (384 blocks)
  k_gemm_qkv<<<dim3(24, 16), 256, 0, stream>>>(xb, WqT, cosb, sinb, qg, kg, Qb, Kb, Vb, 2048);
  k_vtrans<<<dim3(32, 8), 256, 0, stream>>>(Vb, Vt);
  k_attn<<<512, 512, 0, stream>>>(Qb, Kb, Vt, attnb);
  // output projection: 256 blocks, direct f32 store (no split-K, no memset)
  k_gemm_out<<<dim3(16, 16), 256, 0, stream>>>(attnb, WoT, out, 2048, 2048, 2048, 2048);
}

// Round 12
// 168.570 us; speedup vs baseline: 1.5300x; 1.1725x over previous
//
#include <hip/hip_runtime.h>
#include <hip/hip_bf16.h>
#include <stdint.h>

typedef __hip_bfloat16 bf16;
typedef __attribute__((ext_vector_type(4))) short short4v;
typedef __attribute__((ext_vector_type(8))) short short8v;
typedef __attribute__((ext_vector_type(4))) float f32x4;

#define CAT8(lo,hi) __builtin_shufflevector(lo, hi, 0,1,2,3,4,5,6,7)
#define MFMA16(a,b,c) __builtin_amdgcn_mfma_f32_16x16x32_bf16(a,b,c,0,0,0)

__device__ __forceinline__ void gload16(const void* g, void* l) {
  __builtin_amdgcn_global_load_lds((const __attribute__((address_space(1))) unsigned int*)g,
                                   (__attribute__((address_space(3))) unsigned int*)l, 16, 0, 0);
}

__device__ __forceinline__ short f2bs(float f) {
  return __builtin_bit_cast(short, __float2bfloat16(f));
}

// K-dim permutation within each 32-group: lane-group g's MFMA fragment
// {4g..4g+3, 16+4g..16+4g+3} becomes 8 CONTIGUOUS elements at 8g..8g+7.
// p(k) = ((k&15)>>2)*8 + ((k>>4)&1)*4 + (k&3)
// GEMM operands (xb, WqT/WkT/WvT, attnb, WoT) live in this layout; both A and B
// are permuted identically so MFMA elementwise k-pairing is preserved.

// ---------------- merged prelude: cvt_x (permuted) + 4 transpose_cvt (permuted) ----------------
__global__ __launch_bounds__(256) void k_prep(const float* __restrict__ x,
    const float* __restrict__ Wq, const float* __restrict__ Wk,
    const float* __restrict__ Wv, const float* __restrict__ Wo,
    bf16* __restrict__ xb, bf16* __restrict__ WqT, bf16* __restrict__ WkT,
    bf16* __restrict__ WvT, bf16* __restrict__ WoT) {
  __shared__ float ts[64][65];
  const int bid = blockIdx.x;
  const int t = threadIdx.x;
  if (bid < 4096) {
    // x [2048][2048] f32 -> xb bf16, K-permuted columns (4-aligned groups map contiguously)
    int f = (bid*256 + t)*4;
    int row = f >> 11, c = f & 2047;
    float4 v = *(const float4*)(x + (size_t)row*2048 + c);
    int pc = (c & ~31) | (((c & 15) >> 2) << 3) | (((c >> 4) & 1) << 2);
    short4v o;
    o[0] = f2bs(v.x); o[1] = f2bs(v.y); o[2] = f2bs(v.z); o[3] = f2bs(v.w);
    *(short4v*)(xb + (size_t)row*2048 + pc) = o;
    return;
  }
  int tb = bid - 4096;
  const float* W; bf16* Wt; int K, N, bx, by;
  if (tb < 1024)      { W = Wq; Wt = WqT; K = 2048; N = 2048; bx = tb & 31;         by = tb >> 5; }
  else if (tb < 1280) { W = Wk; Wt = WkT; K = 2048; N = 512;  bx = (tb-1024) & 7;   by = (tb-1024) >> 3; }
  else if (tb < 1536) { W = Wv; Wt = WvT; K = 2048; N = 512;  bx = (tb-1280) & 7;   by = (tb-1280) >> 3; }
  else                { W = Wo; Wt = WoT; K = 2048; N = 2048; bx = (tb-1536) & 31;  by = (tb-1536) >> 5; }
  const int k0 = by*64, n0 = bx*64;
  #pragma unroll
  for (int ii = 0; ii < 16; ++ii) {
    int idx = ii*256 + t; int r = idx>>6, c = idx&63;
    ts[r][c] = W[(size_t)(k0+r)*N + n0 + c];
  }
  __syncthreads();
  #pragma unroll
  for (int ii = 0; ii < 16; ++ii) {
    int idx = ii*256 + t; int r = idx>>6, c = idx&63;   // r: n-row, c: k-col (logical)
    int pc = (c & 32) | (((c & 15) >> 2) << 3) | (((c >> 4) & 1) << 2) | (c & 3);
    Wt[(size_t)(n0+r)*K + k0 + pc] = __float2bfloat16(ts[c][r]);
  }
}

// ---------------- QKV GEMM, FUSED RMSNorm+RoPE epilogue, b128 frags ----------------
// 128x128 tile, BK=32, 4 waves 2x2, depth-2 prefetch (tri-buffer), chunk-XOR swizzle.
// K-permuted operands: each lane's fragment = ONE aligned ds_read_b128 (was 2x b64 + repack).
__global__ __launch_bounds__(256) void k_gemm_qkv(const bf16* __restrict__ A, const bf16* __restrict__ Bt,
                                                  const float* __restrict__ cosb, const float* __restrict__ sinb,
                                                  const float* __restrict__ qg, const float* __restrict__ kg,
                                                  bf16* __restrict__ Qb, bf16* __restrict__ Kb,
                                                  bf16* __restrict__ Vb, int K) {
  __shared__ bf16 Asm[3][128*32];
  __shared__ bf16 Bsm[3][128*32];
  const int t = threadIdx.x;
  const int lane = t & 63, w = t >> 6;
  const int wr = w >> 1, wc = w & 1;
  const int m0 = blockIdx.y*128, n0 = blockIdx.x*128;
  const int l15 = lane & 15;
  const int g16 = (lane >> 4) << 4;        // 16-B chunk of this lane group

  f32x4 acc[4][4];
  #pragma unroll
  for (int i = 0; i < 4; ++i)
    #pragma unroll
    for (int j = 0; j < 4; ++j) acc[i][j] = 0.f;

  const char* Ab = (const char*)A;
  const char* Bb = (const char*)Bt;
  const int off  = t*16;
  const int srow = off >> 6;
  const int scolb = (((off >> 4) & 3) ^ ((srow >> 1) & 3)) << 4;

  const size_t arow0 = (size_t)(m0+srow)*K, arow1 = (size_t)(m0+srow+64)*K;
  const size_t brow0 = (size_t)(n0+srow)*K, brow1 = (size_t)(n0+srow+64)*K;

#define STAGE(buf, kk)  do {                                          \
    gload16(Ab + (arow0 + (kk))*2 + scolb, (char*)Asm[buf] + off);    \
    gload16(Ab + (arow1 + (kk))*2 + scolb, (char*)Asm[buf] + off + 4096); \
    gload16(Bb + (brow0 + (kk))*2 + scolb, (char*)Bsm[buf] + off);    \
    gload16(Bb + (brow1 + (kk))*2 + scolb, (char*)Bsm[buf] + off + 4096); \
  } while (0)

  const int nsteps = K >> 5;
  STAGE(0, 0);
  STAGE(1, 32);

  for (int it = 0; it < nsteps; ++it) {
    const int kf = (it + 2) << 5;
    if (kf < K) {
      STAGE((it + 2) % 3, kf);
      asm volatile("s_waitcnt vmcnt(8)" ::: "memory");
    } else if (it + 1 < nsteps) {
      asm volatile("s_waitcnt vmcnt(4)" ::: "memory");
    } else {
      asm volatile("s_waitcnt vmcnt(0)" ::: "memory");
    }
    __builtin_amdgcn_s_barrier();
    __builtin_amdgcn_sched_barrier(0);

    const char* Ac = (const char*)Asm[it % 3];
    const char* Bc = (const char*)Bsm[it % 3];
    short8v a[4], b[4];
    #pragma unroll
    for (int i = 0; i < 4; ++i) {
      const int arow = wr*64 + i*16 + l15;
      a[i] = *(const short8v*)(Ac + arow*64 + (g16 ^ (((arow >> 1) & 3) << 4)));
      const int brow = wc*64 + i*16 + l15;
      b[i] = *(const short8v*)(Bc + brow*64 + (g16 ^ (((brow >> 1) & 3) << 4)));
    }
    #pragma unroll
    for (int i = 0; i < 4; ++i)
      #pragma unroll
      for (int j = 0; j < 4; ++j)
        acc[i][j] = MFMA16(a[i], b[j], acc[i][j]);
    __builtin_amdgcn_sched_barrier(0);
    __builtin_amdgcn_s_barrier();
  }
#undef STAGE

  // ---- fused epilogue: rmsnorm + rope (Q/K) or plain cvt (V); outputs in LOGICAL layout ----
  const int hh = (n0 + wc*64) >> 6;            // head id 0..47 (wave-uniform)
  float gam[4];
  if (hh < 40) {
    const float* gp = (hh < 32) ? qg : kg;
    #pragma unroll
    for (int j = 0; j < 4; ++j) gam[j] = gp[j*16 + l15];
  }
  #pragma unroll
  for (int i = 0; i < 4; ++i) {
    #pragma unroll
    for (int rr = 0; rr < 4; ++rr) {
      const int row = m0 + wr*64 + i*16 + ((lane>>4)<<2) + rr;   // absolute s
      float v0 = acc[i][0][rr], v1 = acc[i][1][rr], v2 = acc[i][2][rr], v3 = acc[i][3][rr];
      if (hh < 40) {
        float ss = v0*v0 + v1*v1 + v2*v2 + v3*v3;
        ss += __shfl_xor(ss, 1); ss += __shfl_xor(ss, 2);
        ss += __shfl_xor(ss, 4); ss += __shfl_xor(ss, 8);
        const float rms = rsqrtf(ss*(1.0f/64.0f) + 1e-6f);
        const float t0 = v0*rms*gam[0], t1 = v1*rms*gam[1];
        const float t2 = v2*rms*gam[2], t3 = v3*rms*gam[3];
        const float* cr = cosb + (size_t)row*64;
        const float* sr = sinb + (size_t)row*64;
        const float o0 = t0*cr[l15]      - t2*sr[l15];
        const float o1 = t1*cr[16+l15]   - t3*sr[16+l15];
        const float o2 = t2*cr[32+l15]   + t0*sr[32+l15];
        const float o3 = t3*cr[48+l15]   + t1*sr[48+l15];
        bf16* dst = (hh < 32) ? (Qb + ((size_t)hh*2048 + row)*64)
                              : (Kb + ((size_t)(hh-32)*2048 + row)*64);
        dst[l15]      = __float2bfloat16(o0);
        dst[16 + l15] = __float2bfloat16(o1);
        dst[32 + l15] = __float2bfloat16(o2);
        dst[48 + l15] = __float2bfloat16(o3);
      } else {
        bf16* dst = Vb + ((size_t)(hh-40)*2048 + row)*64;
        dst[l15]      = __float2bfloat16(v0);
        dst[16 + l15] = __float2bfloat16(v1);
        dst[32 + l15] = __float2bfloat16(v2);
        dst[48 + l15] = __float2bfloat16(v3);
      }
    }
  }
}

// ---------------- out-proj GEMM: direct f32 store, b128 frags, depth-2 prefetch ----------------
__global__ __launch_bounds__(256) void k_gemm_out(const bf16* __restrict__ A, const bf16* __restrict__ Bt,
                                                  float* __restrict__ C, int M, int N, int K, int ldc) {
  __shared__ bf16 Asm[3][128*32];
  __shared__ bf16 Bsm[3][128*32];
  const int t = threadIdx.x;
  const int lane = t & 63, w = t >> 6;
  const int wr = w >> 1, wc = w & 1;
  const int m0 = blockIdx.y*128, n0 = blockIdx.x*128;
  const int l15 = lane & 15;
  const int g16 = (lane >> 4) << 4;

  f32x4 acc[4][4];
  #pragma unroll
  for (int i = 0; i < 4; ++i)
    #pragma unroll
    for (int j = 0; j < 4; ++j) acc[i][j] = 0.f;

  const char* Ab = (const char*)A;
  const char* Bb = (const char*)Bt;
  const int off  = t*16;
  const int srow = off >> 6;
  const int scolb = (((off >> 4) & 3) ^ ((srow >> 1) & 3)) << 4;

  const size_t arow0 = (size_t)(m0+srow)*K, arow1 = (size_t)(m0+srow+64)*K;
  const size_t brow0 = (size_t)(n0+srow)*K, brow1 = (size_t)(n0+srow+64)*K;

#define STAGE(buf, kk)  do {                                          \
    gload16(Ab + (arow0 + (kk))*2 + scolb, (char*)Asm[buf] + off);    \
    gload16(Ab + (arow1 + (kk))*2 + scolb, (char*)Asm[buf] + off + 4096); \
    gload16(Bb + (brow0 + (kk))*2 + scolb, (char*)Bsm[buf] + off);    \
    gload16(Bb + (brow1 + (kk))*2 + scolb, (char*)Bsm[buf] + off + 4096); \
  } while (0)

  const int nsteps = K >> 5;
  STAGE(0, 0);
  STAGE(1, 32);

  for (int it = 0; it < nsteps; ++it) {
    if (it + 2 < nsteps) {
      STAGE((it + 2) % 3, (it + 2) << 5);
      asm volatile("s_waitcnt vmcnt(8)" ::: "memory");
    } else if (it + 1 < nsteps) {
      asm volatile("s_waitcnt vmcnt(4)" ::: "memory");
    } else {
      asm volatile("s_waitcnt vmcnt(0)" ::: "memory");
    }
    __builtin_amdgcn_s_barrier();
    __builtin_amdgcn_sched_barrier(0);

    const char* Ac = (const char*)Asm[it % 3];
    const char* Bc = (const char*)Bsm[it % 3];
    short8v a[4], b[4];
    #pragma unroll
    for (int i = 0; i < 4; ++i) {
      const int arow = wr*64 + i*16 + l15;
      a[i] = *(const short8v*)(Ac + arow*64 + (g16 ^ (((arow >> 1) & 3) << 4)));
      const int brow = wc*64 + i*16 + l15;
      b[i] = *(const short8v*)(Bc + brow*64 + (g16 ^ (((brow >> 1) & 3) << 4)));
    }
    #pragma unroll
    for (int i = 0; i < 4; ++i)
      #pragma unroll
      for (int j = 0; j < 4; ++j)
        acc[i][j] = MFMA16(a[i], b[j], acc[i][j]);
    __builtin_amdgcn_sched_barrier(0);
    __builtin_amdgcn_s_barrier();
  }
#undef STAGE

  #pragma unroll
  for (int i = 0; i < 4; ++i) {
    int row0 = m0 + wr*64 + i*16 + ((lane>>4)<<2);
    #pragma unroll
    for (int j = 0; j < 4; ++j) {
      int col = n0 + wc*64 + j*16 + l15;
      #pragma unroll
      for (int r = 0; r < 4; ++r)
        C[(size_t)(row0+r)*ldc + col] = acc[i][j][r];
    }
  }
}

// ---------------- V transpose: Vb [8][2048][64] -> Vt [8][64][2048] ----------------
__global__ __launch_bounds__(256) void k_vtrans(const bf16* __restrict__ Vb, bf16* __restrict__ Vt) {
  __shared__ bf16 ts[64][72];
  const int kv = blockIdx.y;
  const int s0 = blockIdx.x*64;
  const int t  = threadIdx.x;
  const bf16* src = Vb + ((size_t)kv*2048 + s0)*64;
  #pragma unroll
  for (int ii = 0; ii < 2; ++ii) {
    int idx = ii*256 + t;
    int s = idx >> 3, d8 = (idx & 7)*8;
    *(int4*)&ts[s][d8] = *(const int4*)(src + s*64 + d8);
  }
  __syncthreads();
  #pragma unroll
  for (int ii = 0; ii < 2; ++ii) {
    int idx = ii*256 + t;
    int d = idx >> 3, sB = (idx & 7)*8;
    short8v v;
    #pragma unroll
    for (int e = 0; e < 8; ++e) v[e] = __builtin_bit_cast(short, ts[sB+e][d]);
    *(short8v*)(Vt + (size_t)kv*64*2048 + (size_t)d*2048 + s0 + sB) = v;
  }
}

// ---------------- causal flash attention v4: KVBLK=128, K-permuted output writes ----------------
#define SCALE2 0.18033688011f   /* (1/sqrt(64)) * log2(e) */
__global__ __launch_bounds__(512) void k_attn(const bf16* __restrict__ Qb, const bf16* __restrict__ Kb,
                                              const bf16* __restrict__ Vt, bf16* __restrict__ attnb) {
  __shared__ bf16 Ksm[128][68];
  __shared__ bf16 Vsm[64][132];
  const int t = threadIdx.x, lane = t & 63, w = t >> 6;
  const int bid = blockIdx.x;
  const int h = bid & 31;
  const int qi = 15 - (bid >> 5);          // heavy blocks first
  const int qb0 = qi * 128;
  const int kvh = h >> 2;
  const int kb = (lane>>4)*4;
  const int l15 = lane & 15;

  const bf16* Qh = Qb + (size_t)h*2048*64;
  const bf16* Kh = Kb + (size_t)kvh*2048*64;
  const bf16* Vh = Vt + (size_t)kvh*64*2048;

  const int qrow = qb0 + w*16 + l15;       // this lane's q-row (replicated x4 groups)
  short4v qlo[2], qhi[2];
  #pragma unroll
  for (int kk = 0; kk < 2; ++kk) {
    qlo[kk] = *(const short4v*)(Qh + (size_t)qrow*64 + kk*32 + kb);
    qhi[kk] = *(const short4v*)(Qh + (size_t)qrow*64 + kk*32 + 16 + kb);
  }

  float m_ = -3e38f, ls = 0.f;
  f32x4 o2[4];
  #pragma unroll
  for (int j = 0; j < 4; ++j) o2[j] = 0.f;

  const int nt = qi + 1;
  for (int tt = 0; tt < nt; ++tt) {
    #pragma unroll
    for (int ii = 0; ii < 2; ++ii) {
      int idx = ii*512 + t;
      int kr = idx >> 3, kc = (idx & 7)*8;
      *(int4*)(&Ksm[kr][kc]) = *(const int4*)(Kh + ((size_t)(tt*128 + kr))*64 + kc);
      int vr = idx >> 4, vc = (idx & 15)*8;
      *(int4*)(&Vsm[vr][vc]) = *(const int4*)(Vh + (size_t)vr*2048 + tt*128 + vc);
    }
    __syncthreads();

    // S^T = K Q^T -> sAcc[j]: kv-block j (0..7), q = l15
    f32x4 sAcc[8];
    #pragma unroll
    for (int j = 0; j < 8; ++j) sAcc[j] = 0.f;
    __builtin_amdgcn_s_setprio(1);
    #pragma unroll
    for (int kk = 0; kk < 2; ++kk) {
      short8v bq = CAT8(qlo[kk], qhi[kk]);
      #pragma unroll
      for (int j = 0; j < 8; ++j) {
        const bf16* kp = &Ksm[j*16 + l15][kk*32 + kb];
        short8v ak = CAT8(*(const short4v*)kp, *(const short4v*)(kp + 16));
        sAcc[j] = MFMA16(ak, bq, sAcc[j]);
      }
    }
    __builtin_amdgcn_s_setprio(0);

    float p[8][4];
    #pragma unroll
    for (int j = 0; j < 8; ++j)
      #pragma unroll
      for (int r = 0; r < 4; ++r) p[j][r] = sAcc[j][r]*SCALE2;
    if (tt == nt - 1) {                      // diagonal tile: causal mask
      #pragma unroll
      for (int j = 0; j < 8; ++j) {
        #pragma unroll
        for (int r = 0; r < 4; ++r)
          if (tt*128 + j*16 + kb + r > qrow) p[j][r] = -3e38f;
      }
    }

    float mx = p[0][0];
    #pragma unroll
    for (int j = 0; j < 8; ++j)
      #pragma unroll
      for (int r = 0; r < 4; ++r) mx = fmaxf(mx, p[j][r]);
    mx = fmaxf(mx, __shfl_xor(mx, 16));
    mx = fmaxf(mx, __shfl_xor(mx, 32));
    float mn = fmaxf(m_, mx);
    float alpha = exp2f(m_ - mn);
    m_ = mn;
    ls *= alpha;
    #pragma unroll
    for (int j = 0; j < 4; ++j) o2[j] *= alpha;

    float rs = 0.f;
    #pragma unroll
    for (int j = 0; j < 8; ++j)
      #pragma unroll
      for (int r = 0; r < 4; ++r) {
        float e = exp2f(p[j][r] - mn);
        p[j][r] = e;
        rs += e;
      }
    rs += __shfl_xor(rs, 16);
    rs += __shfl_xor(rs, 32);
    ls += rs;

    short8v pb[4];
    #pragma unroll
    for (int kk = 0; kk < 4; ++kk) {
      short8v v;
      v[0] = f2bs(p[2*kk][0]);   v[1] = f2bs(p[2*kk][1]);
      v[2] = f2bs(p[2*kk][2]);   v[3] = f2bs(p[2*kk][3]);
      v[4] = f2bs(p[2*kk+1][0]); v[5] = f2bs(p[2*kk+1][1]);
      v[6] = f2bs(p[2*kk+1][2]); v[7] = f2bs(p[2*kk+1][3]);
      pb[kk] = v;
    }

    __builtin_amdgcn_s_setprio(1);
    #pragma unroll
    for (int kk = 0; kk < 4; ++kk) {
      #pragma unroll
      for (int j = 0; j < 4; ++j) {
        const bf16* vp = &Vsm[j*16 + l15][kk*32 + kb];
        short8v av = CAT8(*(const short4v*)vp, *(const short4v*)(vp + 16));
        o2[j] = MFMA16(av, pb[kk], o2[j]);
      }
    }
    __builtin_amdgcn_s_setprio(0);
    __syncthreads();
  }

  // write attnb in K-PERMUTED layout (out-proj A-operand): logical col h*64+j*16+kb+r
  // -> permuted col h*64 + (j>>1)*32 + 2*kb + 4*(j&1) + r ; r=0..3 contiguous -> b64 store
  float inv = 1.0f / ls;
  #pragma unroll
  for (int j = 0; j < 4; ++j) {
    short4v vv;
    vv[0] = f2bs(o2[j][0]*inv); vv[1] = f2bs(o2[j][1]*inv);
    vv[2] = f2bs(o2[j][2]*inv); vv[3] = f2bs(o2[j][3]*inv);
    *(short4v*)(attnb + (size_t)qrow*2048 + h*64 + (j>>1)*32 + (kb<<1) + ((j&1)<<2)) = vv;
  }
}

extern "C" void kernel_launch(void* const* d_in, const int* in_sizes, int n_in,
                              void* d_out, int out_size, void* d_ws, size_t ws_size,
                              hipStream_t stream) {
  const float* x    = (const float*)d_in[0];
  const float* cosb = (const float*)d_in[2];
  const float* sinb = (const float*)d_in[3];
  const float* Wq   = (const float*)d_in[4];
  const float* Wk   = (const float*)d_in[5];
  const float* Wv   = (const float*)d_in[6];
  const float* Wo   = (const float*)d_in[7];
  const float* qg   = (const float*)d_in[8];
  const float* kg   = (const float*)d_in[9];
  float* out = (float*)d_out;

  char* ws = (char*)d_ws;
  bf16*  xb    = (bf16*)(ws);                    // 8 MB  [2048][2048] K-perm (live thru QKV GEMM)
  bf16*  WqT   = (bf16*)(ws + 8388608);          // 8 MB  K-perm
  bf16*  WkT   = (bf16*)(ws + 16777216);         // 2 MB  K-perm
  bf16*  WvT   = (bf16*)(ws + 18874368);         // 2 MB  K-perm (contiguous N=3072 B-panel)
  bf16*  WoT   = (bf16*)(ws + 20971520);         // 8 MB  K-perm (live until out-proj)
  bf16*  Qb    = (bf16*)(ws + 29360128);         // 8 MB  [32][2048][64] logical
  bf16*  Kb    = (bf16*)(ws + 37748736);         // 2 MB  [8][2048][64] logical
  bf16*  Vb    = (bf16*)(ws + 39845888);         // 2 MB  [8][2048][64] logical
  bf16*  Vt    = (bf16*)(ws + 41943040);         // 2 MB  [8][64][2048] logical
  bf16*  attnb = (bf16*)(ws);                    // 8 MB  K-perm (overlays dead xb)

  // merged prelude: cvt_x (4096 blocks) + 4 transposes (2560 blocks)
  k_prep<<<6656, 256, 0, stream>>>(x, Wq, Wk, Wv, Wo, xb, WqT, WkT, WvT, WoT);

  // QKV projection + fused RMSNorm/RoPE epilogue (384 blocks)
  k_gemm_qkv<<<dim3(24, 16), 256, 0, stream>>>(xb, WqT, cosb, sinb, qg, kg, Qb, Kb, Vb, 2048);
  k_vtrans<<<dim3(32, 8), 256, 0, stream>>>(Vb, Vt);
  k_attn<<<512, 512, 0, stream>>>(Qb, Kb, Vt, attnb);
  // output projection: 256 blocks, direct f32 store
  k_gemm_out<<<dim3(16, 16), 256, 0, stream>>>(attnb, WoT, out, 2048, 2048, 2048, 2048);
}

// Round 13
// 166.874 us; speedup vs baseline: 1.5455x; 1.0102x over previous
//
#include <hip/hip_runtime.h>
#include <hip/hip_bf16.h>
#include <stdint.h>

typedef __hip_bfloat16 bf16;
typedef __attribute__((ext_vector_type(4))) short short4v;
typedef __attribute__((ext_vector_type(8))) short short8v;
typedef __attribute__((ext_vector_type(4))) float f32x4;

#define CAT8(lo,hi) __builtin_shufflevector(lo, hi, 0,1,2,3,4,5,6,7)
#define MFMA16(a,b,c) __builtin_amdgcn_mfma_f32_16x16x32_bf16(a,b,c,0,0,0)
#define SCALE2 0.18033688011f   /* (1/sqrt(64)) * log2(e) — folded into Qb */

__device__ __forceinline__ void gload16(const void* g, void* l) {
  __builtin_amdgcn_global_load_lds((const __attribute__((address_space(1))) unsigned int*)g,
                                   (__attribute__((address_space(3))) unsigned int*)l, 16, 0, 0);
}

__device__ __forceinline__ short f2bs(float f) {
  return __builtin_bit_cast(short, __float2bfloat16(f));
}

__device__ __forceinline__ float max3f(float a, float b, float c) {
  return fmaxf(fmaxf(a, b), c);      // clang fuses to v_max3_f32 (T17)
}

// K-dim permutation within each 32-group: lane-group g's MFMA fragment
// {4g..4g+3, 16+4g..16+4g+3} becomes 8 CONTIGUOUS elements at 8g..8g+7.
// p(k) = ((k&15)>>2)*8 + ((k>>4)&1)*4 + (k&3)

// ---------------- merged prelude: cvt_x (permuted) + 4 transpose_cvt (permuted) ----------------
__global__ __launch_bounds__(256) void k_prep(const float* __restrict__ x,
    const float* __restrict__ Wq, const float* __restrict__ Wk,
    const float* __restrict__ Wv, const float* __restrict__ Wo,
    bf16* __restrict__ xb, bf16* __restrict__ WqT, bf16* __restrict__ WkT,
    bf16* __restrict__ WvT, bf16* __restrict__ WoT) {
  __shared__ float ts[64][65];
  const int bid = blockIdx.x;
  const int t = threadIdx.x;
  if (bid < 4096) {
    int f = (bid*256 + t)*4;
    int row = f >> 11, c = f & 2047;
    float4 v = *(const float4*)(x + (size_t)row*2048 + c);
    int pc = (c & ~31) | (((c & 15) >> 2) << 3) | (((c >> 4) & 1) << 2);
    short4v o;
    o[0] = f2bs(v.x); o[1] = f2bs(v.y); o[2] = f2bs(v.z); o[3] = f2bs(v.w);
    *(short4v*)(xb + (size_t)row*2048 + pc) = o;
    return;
  }
  int tb = bid - 4096;
  const float* W; bf16* Wt; int K, N, bx, by;
  if (tb < 1024)      { W = Wq; Wt = WqT; K = 2048; N = 2048; bx = tb & 31;         by = tb >> 5; }
  else if (tb < 1280) { W = Wk; Wt = WkT; K = 2048; N = 512;  bx = (tb-1024) & 7;   by = (tb-1024) >> 3; }
  else if (tb < 1536) { W = Wv; Wt = WvT; K = 2048; N = 512;  bx = (tb-1280) & 7;   by = (tb-1280) >> 3; }
  else                { W = Wo; Wt = WoT; K = 2048; N = 2048; bx = (tb-1536) & 31;  by = (tb-1536) >> 5; }
  const int k0 = by*64, n0 = bx*64;
  #pragma unroll
  for (int ii = 0; ii < 16; ++ii) {
    int idx = ii*256 + t; int r = idx>>6, c = idx&63;
    ts[r][c] = W[(size_t)(k0+r)*N + n0 + c];
  }
  __syncthreads();
  #pragma unroll
  for (int ii = 0; ii < 16; ++ii) {
    int idx = ii*256 + t; int r = idx>>6, c = idx&63;   // r: n-row, c: k-col (logical)
    int pc = (c & 32) | (((c & 15) >> 2) << 3) | (((c >> 4) & 1) << 2) | (c & 3);
    Wt[(size_t)(n0+r)*K + k0 + pc] = __float2bfloat16(ts[c][r]);
  }
}

// ---------------- QKV GEMM, FUSED RMSNorm+RoPE epilogue, b128 frags ----------------
// Q-heads additionally scaled by SCALE2 (folded softmax scale).
__global__ __launch_bounds__(256) void k_gemm_qkv(const bf16* __restrict__ A, const bf16* __restrict__ Bt,
                                                  const float* __restrict__ cosb, const float* __restrict__ sinb,
                                                  const float* __restrict__ qg, const float* __restrict__ kg,
                                                  bf16* __restrict__ Qb, bf16* __restrict__ Kb,
                                                  bf16* __restrict__ Vb, int K) {
  __shared__ bf16 Asm[3][128*32];
  __shared__ bf16 Bsm[3][128*32];
  const int t = threadIdx.x;
  const int lane = t & 63, w = t >> 6;
  const int wr = w >> 1, wc = w & 1;
  const int m0 = blockIdx.y*128, n0 = blockIdx.x*128;
  const int l15 = lane & 15;
  const int g16 = (lane >> 4) << 4;

  f32x4 acc[4][4];
  #pragma unroll
  for (int i = 0; i < 4; ++i)
    #pragma unroll
    for (int j = 0; j < 4; ++j) acc[i][j] = 0.f;

  const char* Ab = (const char*)A;
  const char* Bb = (const char*)Bt;
  const int off  = t*16;
  const int srow = off >> 6;
  const int scolb = (((off >> 4) & 3) ^ ((srow >> 1) & 3)) << 4;

  const size_t arow0 = (size_t)(m0+srow)*K, arow1 = (size_t)(m0+srow+64)*K;
  const size_t brow0 = (size_t)(n0+srow)*K, brow1 = (size_t)(n0+srow+64)*K;

#define STAGE(buf, kk)  do {                                          \
    gload16(Ab + (arow0 + (kk))*2 + scolb, (char*)Asm[buf] + off);    \
    gload16(Ab + (arow1 + (kk))*2 + scolb, (char*)Asm[buf] + off + 4096); \
    gload16(Bb + (brow0 + (kk))*2 + scolb, (char*)Bsm[buf] + off);    \
    gload16(Bb + (brow1 + (kk))*2 + scolb, (char*)Bsm[buf] + off + 4096); \
  } while (0)

  const int nsteps = K >> 5;
  STAGE(0, 0);
  STAGE(1, 32);

  for (int it = 0; it < nsteps; ++it) {
    const int kf = (it + 2) << 5;
    if (kf < K) {
      STAGE((it + 2) % 3, kf);
      asm volatile("s_waitcnt vmcnt(8)" ::: "memory");
    } else if (it + 1 < nsteps) {
      asm volatile("s_waitcnt vmcnt(4)" ::: "memory");
    } else {
      asm volatile("s_waitcnt vmcnt(0)" ::: "memory");
    }
    __builtin_amdgcn_s_barrier();
    __builtin_amdgcn_sched_barrier(0);

    const char* Ac = (const char*)Asm[it % 3];
    const char* Bc = (const char*)Bsm[it % 3];
    short8v a[4], b[4];
    #pragma unroll
    for (int i = 0; i < 4; ++i) {
      const int arow = wr*64 + i*16 + l15;
      a[i] = *(const short8v*)(Ac + arow*64 + (g16 ^ (((arow >> 1) & 3) << 4)));
      const int brow = wc*64 + i*16 + l15;
      b[i] = *(const short8v*)(Bc + brow*64 + (g16 ^ (((brow >> 1) & 3) << 4)));
    }
    #pragma unroll
    for (int i = 0; i < 4; ++i)
      #pragma unroll
      for (int j = 0; j < 4; ++j)
        acc[i][j] = MFMA16(a[i], b[j], acc[i][j]);
    __builtin_amdgcn_sched_barrier(0);
    __builtin_amdgcn_s_barrier();
  }
#undef STAGE

  // ---- fused epilogue: rmsnorm + rope (Q/K) or plain cvt (V); outputs in LOGICAL layout ----
  const int hh = (n0 + wc*64) >> 6;            // head id 0..47 (wave-uniform)
  float gam[4];
  if (hh < 40) {
    const float* gp = (hh < 32) ? qg : kg;
    #pragma unroll
    for (int j = 0; j < 4; ++j) gam[j] = gp[j*16 + l15];
    if (hh < 32) {
      #pragma unroll
      for (int j = 0; j < 4; ++j) gam[j] *= SCALE2;   // fold softmax scale into Q
    }
  }
  #pragma unroll
  for (int i = 0; i < 4; ++i) {
    #pragma unroll
    for (int rr = 0; rr < 4; ++rr) {
      const int row = m0 + wr*64 + i*16 + ((lane>>4)<<2) + rr;   // absolute s
      float v0 = acc[i][0][rr], v1 = acc[i][1][rr], v2 = acc[i][2][rr], v3 = acc[i][3][rr];
      if (hh < 40) {
        float ss = v0*v0 + v1*v1 + v2*v2 + v3*v3;
        ss += __shfl_xor(ss, 1); ss += __shfl_xor(ss, 2);
        ss += __shfl_xor(ss, 4); ss += __shfl_xor(ss, 8);
        const float rms = rsqrtf(ss*(1.0f/64.0f) + 1e-6f);
        const float t0 = v0*rms*gam[0], t1 = v1*rms*gam[1];
        const float t2 = v2*rms*gam[2], t3 = v3*rms*gam[3];
        const float* cr = cosb + (size_t)row*64;
        const float* sr = sinb + (size_t)row*64;
        const float o0 = t0*cr[l15]      - t2*sr[l15];
        const float o1 = t1*cr[16+l15]   - t3*sr[16+l15];
        const float o2 = t2*cr[32+l15]   + t0*sr[32+l15];
        const float o3 = t3*cr[48+l15]   + t1*sr[48+l15];
        bf16* dst = (hh < 32) ? (Qb + ((size_t)hh*2048 + row)*64)
                              : (Kb + ((size_t)(hh-32)*2048 + row)*64);
        dst[l15]      = __float2bfloat16(o0);
        dst[16 + l15] = __float2bfloat16(o1);
        dst[32 + l15] = __float2bfloat16(o2);
        dst[48 + l15] = __float2bfloat16(o3);
      } else {
        bf16* dst = Vb + ((size_t)(hh-40)*2048 + row)*64;
        dst[l15]      = __float2bfloat16(v0);
        dst[16 + l15] = __float2bfloat16(v1);
        dst[32 + l15] = __float2bfloat16(v2);
        dst[48 + l15] = __float2bfloat16(v3);
      }
    }
  }
}

// ---------------- out-proj GEMM: direct f32 store, b128 frags, depth-2 prefetch ----------------
__global__ __launch_bounds__(256) void k_gemm_out(const bf16* __restrict__ A, const bf16* __restrict__ Bt,
                                                  float* __restrict__ C, int M, int N, int K, int ldc) {
  __shared__ bf16 Asm[3][128*32];
  __shared__ bf16 Bsm[3][128*32];
  const int t = threadIdx.x;
  const int lane = t & 63, w = t >> 6;
  const int wr = w >> 1, wc = w & 1;
  const int m0 = blockIdx.y*128, n0 = blockIdx.x*128;
  const int l15 = lane & 15;
  const int g16 = (lane >> 4) << 4;

  f32x4 acc[4][4];
  #pragma unroll
  for (int i = 0; i < 4; ++i)
    #pragma unroll
    for (int j = 0; j < 4; ++j) acc[i][j] = 0.f;

  const char* Ab = (const char*)A;
  const char* Bb = (const char*)Bt;
  const int off  = t*16;
  const int srow = off >> 6;
  const int scolb = (((off >> 4) & 3) ^ ((srow >> 1) & 3)) << 4;

  const size_t arow0 = (size_t)(m0+srow)*K, arow1 = (size_t)(m0+srow+64)*K;
  const size_t brow0 = (size_t)(n0+srow)*K, brow1 = (size_t)(n0+srow+64)*K;

#define STAGE(buf, kk)  do {                                          \
    gload16(Ab + (arow0 + (kk))*2 + scolb, (char*)Asm[buf] + off);    \
    gload16(Ab + (arow1 + (kk))*2 + scolb, (char*)Asm[buf] + off + 4096); \
    gload16(Bb + (brow0 + (kk))*2 + scolb, (char*)Bsm[buf] + off);    \
    gload16(Bb + (brow1 + (kk))*2 + scolb, (char*)Bsm[buf] + off + 4096); \
  } while (0)

  const int nsteps = K >> 5;
  STAGE(0, 0);
  STAGE(1, 32);

  for (int it = 0; it < nsteps; ++it) {
    if (it + 2 < nsteps) {
      STAGE((it + 2) % 3, (it + 2) << 5);
      asm volatile("s_waitcnt vmcnt(8)" ::: "memory");
    } else if (it + 1 < nsteps) {
      asm volatile("s_waitcnt vmcnt(4)" ::: "memory");
    } else {
      asm volatile("s_waitcnt vmcnt(0)" ::: "memory");
    }
    __builtin_amdgcn_s_barrier();
    __builtin_amdgcn_sched_barrier(0);

    const char* Ac = (const char*)Asm[it % 3];
    const char* Bc = (const char*)Bsm[it % 3];
    short8v a[4], b[4];
    #pragma unroll
    for (int i = 0; i < 4; ++i) {
      const int arow = wr*64 + i*16 + l15;
      a[i] = *(const short8v*)(Ac + arow*64 + (g16 ^ (((arow >> 1) & 3) << 4)));
      const int brow = wc*64 + i*16 + l15;
      b[i] = *(const short8v*)(Bc + brow*64 + (g16 ^ (((brow >> 1) & 3) << 4)));
    }
    #pragma unroll
    for (int i = 0; i < 4; ++i)
      #pragma unroll
      for (int j = 0; j < 4; ++j)
        acc[i][j] = MFMA16(a[i], b[j], acc[i][j]);
    __builtin_amdgcn_sched_barrier(0);
    __builtin_amdgcn_s_barrier();
  }
#undef STAGE

  #pragma unroll
  for (int i = 0; i < 4; ++i) {
    int row0 = m0 + wr*64 + i*16 + ((lane>>4)<<2);
    #pragma unroll
    for (int j = 0; j < 4; ++j) {
      int col = n0 + wc*64 + j*16 + l15;
      #pragma unroll
      for (int r = 0; r < 4; ++r)
        C[(size_t)(row0+r)*ldc + col] = acc[i][j][r];
    }
  }
}

// ---------------- V transpose: Vb [8][2048][64] -> Vt [8][64][2048] ----------------
__global__ __launch_bounds__(256) void k_vtrans(const bf16* __restrict__ Vb, bf16* __restrict__ Vt) {
  __shared__ bf16 ts[64][72];
  const int kv = blockIdx.y;
  const int s0 = blockIdx.x*64;
  const int t  = threadIdx.x;
  const bf16* src = Vb + ((size_t)kv*2048 + s0)*64;
  #pragma unroll
  for (int ii = 0; ii < 2; ++ii) {
    int idx = ii*256 + t;
    int s = idx >> 3, d8 = (idx & 7)*8;
    *(int4*)&ts[s][d8] = *(const int4*)(src + s*64 + d8);
  }
  __syncthreads();
  #pragma unroll
  for (int ii = 0; ii < 2; ++ii) {
    int idx = ii*256 + t;
    int d = idx >> 3, sB = (idx & 7)*8;
    short8v v;
    #pragma unroll
    for (int e = 0; e < 8; ++e) v[e] = __builtin_bit_cast(short, ts[sB+e][d]);
    *(short8v*)(Vt + (size_t)kv*64*2048 + (size_t)d*2048 + s0 + sB) = v;
  }
}

// ---------------- causal flash attention v5: pre-scaled Q, defer-max, max3 tree ----------------
__global__ __launch_bounds__(512) void k_attn(const bf16* __restrict__ Qb, const bf16* __restrict__ Kb,
                                              const bf16* __restrict__ Vt, bf16* __restrict__ attnb) {
  __shared__ bf16 Ksm[128][68];
  __shared__ bf16 Vsm[64][132];
  const int t = threadIdx.x, lane = t & 63, w = t >> 6;
  const int bid = blockIdx.x;
  const int h = bid & 31;
  const int qi = 15 - (bid >> 5);          // heavy blocks first
  const int qb0 = qi * 128;
  const int kvh = h >> 2;
  const int kb = (lane>>4)*4;
  const int l15 = lane & 15;

  const bf16* Qh = Qb + (size_t)h*2048*64;
  const bf16* Kh = Kb + (size_t)kvh*2048*64;
  const bf16* Vh = Vt + (size_t)kvh*64*2048;

  const int qrow = qb0 + w*16 + l15;       // this lane's q-row (replicated x4 groups)
  short4v qlo[2], qhi[2];
  #pragma unroll
  for (int kk = 0; kk < 2; ++kk) {
    qlo[kk] = *(const short4v*)(Qh + (size_t)qrow*64 + kk*32 + kb);
    qhi[kk] = *(const short4v*)(Qh + (size_t)qrow*64 + kk*32 + 16 + kb);
  }

  float m_ = -3e38f, ls = 0.f;
  f32x4 o2[4];
  #pragma unroll
  for (int j = 0; j < 4; ++j) o2[j] = 0.f;

  const int nt = qi + 1;
  for (int tt = 0; tt < nt; ++tt) {
    #pragma unroll
    for (int ii = 0; ii < 2; ++ii) {
      int idx = ii*512 + t;
      int kr = idx >> 3, kc = (idx & 7)*8;
      *(int4*)(&Ksm[kr][kc]) = *(const int4*)(Kh + ((size_t)(tt*128 + kr))*64 + kc);
      int vr = idx >> 4, vc = (idx & 15)*8;
      *(int4*)(&Vsm[vr][vc]) = *(const int4*)(Vh + (size_t)vr*2048 + tt*128 + vc);
    }
    __syncthreads();

    // S^T = K Q^T -> sAcc[j]: kv-block j (0..7), q = l15 (already x SCALE2 via Q)
    f32x4 sAcc[8];
    #pragma unroll
    for (int j = 0; j < 8; ++j) sAcc[j] = 0.f;
    __builtin_amdgcn_s_setprio(1);
    #pragma unroll
    for (int kk = 0; kk < 2; ++kk) {
      short8v bq = CAT8(qlo[kk], qhi[kk]);
      #pragma unroll
      for (int j = 0; j < 8; ++j) {
        const bf16* kp = &Ksm[j*16 + l15][kk*32 + kb];
        short8v ak = CAT8(*(const short4v*)kp, *(const short4v*)(kp + 16));
        sAcc[j] = MFMA16(ak, bq, sAcc[j]);
      }
    }
    __builtin_amdgcn_s_setprio(0);

    float p[8][4];
    #pragma unroll
    for (int j = 0; j < 8; ++j)
      #pragma unroll
      for (int r = 0; r < 4; ++r) p[j][r] = sAcc[j][r];
    if (tt == nt - 1) {                      // diagonal tile: causal mask
      #pragma unroll
      for (int j = 0; j < 8; ++j) {
        #pragma unroll
        for (int r = 0; r < 4; ++r)
          if (tt*128 + j*16 + kb + r > qrow) p[j][r] = -3e38f;
      }
    }

    // row max: max3 tree (20 ops) + cross-group combine
    float mj[8];
    #pragma unroll
    for (int j = 0; j < 8; ++j)
      mj[j] = fmaxf(max3f(p[j][0], p[j][1], p[j][2]), p[j][3]);
    float mx = fmaxf(max3f(mj[0], mj[1], mj[2]), max3f(mj[3], mj[4], mj[5]));
    mx = max3f(mx, mj[6], mj[7]);
    mx = fmaxf(mx, __shfl_xor(mx, 16));
    mx = fmaxf(mx, __shfl_xor(mx, 32));

    // defer-max (T13): skip rescale when tile max within 8 of running max (exp2 dom: P <= 256)
    float mn = m_;
    if (!__all(mx <= m_ + 8.f)) {
      mn = fmaxf(m_, mx);
      float alpha = exp2f(m_ - mn);
      m_ = mn;
      ls *= alpha;
      #pragma unroll
      for (int j = 0; j < 4; ++j) o2[j] *= alpha;
    }

    float rs = 0.f;
    #pragma unroll
    for (int j = 0; j < 8; ++j)
      #pragma unroll
      for (int r = 0; r < 4; ++r) {
        float e = exp2f(p[j][r] - mn);
        p[j][r] = e;
        rs += e;
      }
    rs += __shfl_xor(rs, 16);
    rs += __shfl_xor(rs, 32);
    ls += rs;

    short8v pb[4];
    #pragma unroll
    for (int kk = 0; kk < 4; ++kk) {
      short8v v;
      v[0] = f2bs(p[2*kk][0]);   v[1] = f2bs(p[2*kk][1]);
      v[2] = f2bs(p[2*kk][2]);   v[3] = f2bs(p[2*kk][3]);
      v[4] = f2bs(p[2*kk+1][0]); v[5] = f2bs(p[2*kk+1][1]);
      v[6] = f2bs(p[2*kk+1][2]); v[7] = f2bs(p[2*kk+1][3]);
      pb[kk] = v;
    }

    __builtin_amdgcn_s_setprio(1);
    #pragma unroll
    for (int kk = 0; kk < 4; ++kk) {
      #pragma unroll
      for (int j = 0; j < 4; ++j) {
        const bf16* vp = &Vsm[j*16 + l15][kk*32 + kb];
        short8v av = CAT8(*(const short4v*)vp, *(const short4v*)(vp + 16));
        o2[j] = MFMA16(av, pb[kk], o2[j]);
      }
    }
    __builtin_amdgcn_s_setprio(0);
    __syncthreads();
  }

  // write attnb in K-PERMUTED layout (out-proj A-operand)
  float inv = 1.0f / ls;
  #pragma unroll
  for (int j = 0; j < 4; ++j) {
    short4v vv;
    vv[0] = f2bs(o2[j][0]*inv); vv[1] = f2bs(o2[j][1]*inv);
    vv[2] = f2bs(o2[j][2]*inv); vv[3] = f2bs(o2[j][3]*inv);
    *(short4v*)(attnb + (size_t)qrow*2048 + h*64 + (j>>1)*32 + (kb<<1) + ((j&1)<<2)) = vv;
  }
}

extern "C" void kernel_launch(void* const* d_in, const int* in_sizes, int n_in,
                              void* d_out, int out_size, void* d_ws, size_t ws_size,
                              hipStream_t stream) {
  const float* x    = (const float*)d_in[0];
  const float* cosb = (const float*)d_in[2];
  const float* sinb = (const float*)d_in[3];
  const float* Wq   = (const float*)d_in[4];
  const float* Wk   = (const float*)d_in[5];
  const float* Wv   = (const float*)d_in[6];
  const float* Wo   = (const float*)d_in[7];
  const float* qg   = (const float*)d_in[8];
  const float* kg   = (const float*)d_in[9];
  float* out = (float*)d_out;

  char* ws = (char*)d_ws;
  bf16*  xb    = (bf16*)(ws);                    // 8 MB  K-perm (live thru QKV GEMM)
  bf16*  WqT   = (bf16*)(ws + 8388608);          // 8 MB  K-perm
  bf16*  WkT   = (bf16*)(ws + 16777216);         // 2 MB  K-perm
  bf16*  WvT   = (bf16*)(ws + 18874368);         // 2 MB  K-perm (contiguous N=3072 B-panel)
  bf16*  WoT   = (bf16*)(ws + 20971520);         // 8 MB  K-perm (live until out-proj)
  bf16*  Qb    = (bf16*)(ws + 29360128);         // 8 MB  [32][2048][64] logical, x SCALE2
  bf16*  Kb    = (bf16*)(ws + 37748736);         // 2 MB  [8][2048][64] logical
  bf16*  Vb    = (bf16*)(ws + 39845888);         // 2 MB  [8][2048][64] logical
  bf16*  Vt    = (bf16*)(ws + 41943040);         // 2 MB  [8][64][2048] logical
  bf16*  attnb = (bf16*)(ws);                    // 8 MB  K-perm (overlays dead xb)

  k_prep<<<6656, 256, 0, stream>>>(x, Wq, Wk, Wv, Wo, xb, WqT, WkT, WvT, WoT);
  k_gemm_qkv<<<dim3(24, 16), 256, 0, stream>>>(xb, WqT, cosb, sinb, qg, kg, Qb, Kb, Vb, 2048);
  k_vtrans<<<dim3(32, 8), 256, 0, stream>>>(Vb, Vt);
  k_attn<<<512, 512, 0, stream>>>(Qb, Kb, Vt, attnb);
  k_gemm_out<<<dim3(16, 16), 256, 0, stream>>>(attnb, WoT, out, 2048, 2048, 2048, 2048);
}

// Round 14
// 163.410 us; speedup vs baseline: 1.5783x; 1.0212x over previous
//
#include <hip/hip_runtime.h>
#include <hip/hip_bf16.h>
#include <stdint.h>

typedef __hip_bfloat16 bf16;
typedef __attribute__((ext_vector_type(4))) short short4v;
typedef __attribute__((ext_vector_type(8))) short short8v;
typedef __attribute__((ext_vector_type(4))) float f32x4;

#define CAT8(lo,hi) __builtin_shufflevector(lo, hi, 0,1,2,3,4,5,6,7)
#define MFMA16(a,b,c) __builtin_amdgcn_mfma_f32_16x16x32_bf16(a,b,c,0,0,0)
#define SCALE2 0.18033688011f   /* (1/sqrt(64)) * log2(e) — folded into Qb */

__device__ __forceinline__ void gload16(const void* g, void* l) {
  __builtin_amdgcn_global_load_lds((const __attribute__((address_space(1))) unsigned int*)g,
                                   (__attribute__((address_space(3))) unsigned int*)l, 16, 0, 0);
}

__device__ __forceinline__ short f2bs(float f) {
  return __builtin_bit_cast(short, __float2bfloat16(f));
}

__device__ __forceinline__ float max3f(float a, float b, float c) {
  return fmaxf(fmaxf(a, b), c);      // clang fuses to v_max3_f32 (T17)
}

// K-dim permutation within each 32-group: lane-group g's MFMA fragment
// {4g..4g+3, 16+4g..16+4g+3} becomes 8 CONTIGUOUS elements at 8g..8g+7.
// p(k) = ((k&15)>>2)*8 + ((k>>4)&1)*4 + (k&3)
// Applied to: GEMM K-dims (xb/W*/attnb, R12) and NOW to attn's reduction dims:
// d-perm on Qb/Kb (QK^T), kv-perm on Vt columns (PV). Both operands of each
// MFMA permuted identically -> elementwise k-pairing preserved, math bit-exact.

// ---------------- merged prelude: cvt_x (permuted) + 4 transpose_cvt (permuted) ----------------
__global__ __launch_bounds__(256) void k_prep(const float* __restrict__ x,
    const float* __restrict__ Wq, const float* __restrict__ Wk,
    const float* __restrict__ Wv, const float* __restrict__ Wo,
    bf16* __restrict__ xb, bf16* __restrict__ WqT, bf16* __restrict__ WkT,
    bf16* __restrict__ WvT, bf16* __restrict__ WoT) {
  __shared__ float ts[64][65];
  const int bid = blockIdx.x;
  const int t = threadIdx.x;
  if (bid < 4096) {
    int f = (bid*256 + t)*4;
    int row = f >> 11, c = f & 2047;
    float4 v = *(const float4*)(x + (size_t)row*2048 + c);
    int pc = (c & ~31) | (((c & 15) >> 2) << 3) | (((c >> 4) & 1) << 2);
    short4v o;
    o[0] = f2bs(v.x); o[1] = f2bs(v.y); o[2] = f2bs(v.z); o[3] = f2bs(v.w);
    *(short4v*)(xb + (size_t)row*2048 + pc) = o;
    return;
  }
  int tb = bid - 4096;
  const float* W; bf16* Wt; int K, N, bx, by;
  if (tb < 1024)      { W = Wq; Wt = WqT; K = 2048; N = 2048; bx = tb & 31;         by = tb >> 5; }
  else if (tb < 1280) { W = Wk; Wt = WkT; K = 2048; N = 512;  bx = (tb-1024) & 7;   by = (tb-1024) >> 3; }
  else if (tb < 1536) { W = Wv; Wt = WvT; K = 2048; N = 512;  bx = (tb-1280) & 7;   by = (tb-1280) >> 3; }
  else                { W = Wo; Wt = WoT; K = 2048; N = 2048; bx = (tb-1536) & 31;  by = (tb-1536) >> 5; }
  const int k0 = by*64, n0 = bx*64;
  #pragma unroll
  for (int ii = 0; ii < 16; ++ii) {
    int idx = ii*256 + t; int r = idx>>6, c = idx&63;
    ts[r][c] = W[(size_t)(k0+r)*N + n0 + c];
  }
  __syncthreads();
  #pragma unroll
  for (int ii = 0; ii < 16; ++ii) {
    int idx = ii*256 + t; int r = idx>>6, c = idx&63;   // r: n-row, c: k-col (logical)
    int pc = (c & 32) | (((c & 15) >> 2) << 3) | (((c >> 4) & 1) << 2) | (c & 3);
    Wt[(size_t)(n0+r)*K + k0 + pc] = __float2bfloat16(ts[c][r]);
  }
}

// ---------------- QKV GEMM, FUSED RMSNorm+RoPE epilogue, b128 frags ----------------
// Q-heads additionally scaled by SCALE2. Q/K outputs written with d-PERMUTED
// columns (so attn's QK^T fragments are contiguous b128).
__global__ __launch_bounds__(256) void k_gemm_qkv(const bf16* __restrict__ A, const bf16* __restrict__ Bt,
                                                  const float* __restrict__ cosb, const float* __restrict__ sinb,
                                                  const float* __restrict__ qg, const float* __restrict__ kg,
                                                  bf16* __restrict__ Qb, bf16* __restrict__ Kb,
                                                  bf16* __restrict__ Vb, int K) {
  __shared__ bf16 Asm[3][128*32];
  __shared__ bf16 Bsm[3][128*32];
  const int t = threadIdx.x;
  const int lane = t & 63, w = t >> 6;
  const int wr = w >> 1, wc = w & 1;
  const int m0 = blockIdx.y*128, n0 = blockIdx.x*128;
  const int l15 = lane & 15;
  const int g16 = (lane >> 4) << 4;

  f32x4 acc[4][4];
  #pragma unroll
  for (int i = 0; i < 4; ++i)
    #pragma unroll
    for (int j = 0; j < 4; ++j) acc[i][j] = 0.f;

  const char* Ab = (const char*)A;
  const char* Bb = (const char*)Bt;
  const int off  = t*16;
  const int srow = off >> 6;
  const int scolb = (((off >> 4) & 3) ^ ((srow >> 1) & 3)) << 4;

  const size_t arow0 = (size_t)(m0+srow)*K, arow1 = (size_t)(m0+srow+64)*K;
  const size_t brow0 = (size_t)(n0+srow)*K, brow1 = (size_t)(n0+srow+64)*K;

#define STAGE(buf, kk)  do {                                          \
    gload16(Ab + (arow0 + (kk))*2 + scolb, (char*)Asm[buf] + off);    \
    gload16(Ab + (arow1 + (kk))*2 + scolb, (char*)Asm[buf] + off + 4096); \
    gload16(Bb + (brow0 + (kk))*2 + scolb, (char*)Bsm[buf] + off);    \
    gload16(Bb + (brow1 + (kk))*2 + scolb, (char*)Bsm[buf] + off + 4096); \
  } while (0)

  const int nsteps = K >> 5;
  STAGE(0, 0);
  STAGE(1, 32);

  for (int it = 0; it < nsteps; ++it) {
    const int kf = (it + 2) << 5;
    if (kf < K) {
      STAGE((it + 2) % 3, kf);
      asm volatile("s_waitcnt vmcnt(8)" ::: "memory");
    } else if (it + 1 < nsteps) {
      asm volatile("s_waitcnt vmcnt(4)" ::: "memory");
    } else {
      asm volatile("s_waitcnt vmcnt(0)" ::: "memory");
    }
    __builtin_amdgcn_s_barrier();
    __builtin_amdgcn_sched_barrier(0);

    const char* Ac = (const char*)Asm[it % 3];
    const char* Bc = (const char*)Bsm[it % 3];
    short8v a[4], b[4];
    #pragma unroll
    for (int i = 0; i < 4; ++i) {
      const int arow = wr*64 + i*16 + l15;
      a[i] = *(const short8v*)(Ac + arow*64 + (g16 ^ (((arow >> 1) & 3) << 4)));
      const int brow = wc*64 + i*16 + l15;
      b[i] = *(const short8v*)(Bc + brow*64 + (g16 ^ (((brow >> 1) & 3) << 4)));
    }
    #pragma unroll
    for (int i = 0; i < 4; ++i)
      #pragma unroll
      for (int j = 0; j < 4; ++j)
        acc[i][j] = MFMA16(a[i], b[j], acc[i][j]);
    __builtin_amdgcn_sched_barrier(0);
    __builtin_amdgcn_s_barrier();
  }
#undef STAGE

  // ---- fused epilogue: rmsnorm + rope (Q/K, d-PERMUTED store) or plain cvt (V, logical) ----
  const int hh = (n0 + wc*64) >> 6;            // head id 0..47 (wave-uniform)
  float gam[4];
  if (hh < 40) {
    const float* gp = (hh < 32) ? qg : kg;
    #pragma unroll
    for (int j = 0; j < 4; ++j) gam[j] = gp[j*16 + l15];
    if (hh < 32) {
      #pragma unroll
      for (int j = 0; j < 4; ++j) gam[j] *= SCALE2;   // fold softmax scale into Q
    }
  }
  const int pbase = ((l15 >> 2) << 3) + (l15 & 3);   // d-perm base for this lane
  #pragma unroll
  for (int i = 0; i < 4; ++i) {
    #pragma unroll
    for (int rr = 0; rr < 4; ++rr) {
      const int row = m0 + wr*64 + i*16 + ((lane>>4)<<2) + rr;   // absolute s
      float v0 = acc[i][0][rr], v1 = acc[i][1][rr], v2 = acc[i][2][rr], v3 = acc[i][3][rr];
      if (hh < 40) {
        float ss = v0*v0 + v1*v1 + v2*v2 + v3*v3;
        ss += __shfl_xor(ss, 1); ss += __shfl_xor(ss, 2);
        ss += __shfl_xor(ss, 4); ss += __shfl_xor(ss, 8);
        const float rms = rsqrtf(ss*(1.0f/64.0f) + 1e-6f);
        const float t0 = v0*rms*gam[0], t1 = v1*rms*gam[1];
        const float t2 = v2*rms*gam[2], t3 = v3*rms*gam[3];
        const float* cr = cosb + (size_t)row*64;
        const float* sr = sinb + (size_t)row*64;
        const float o0 = t0*cr[l15]      - t2*sr[l15];
        const float o1 = t1*cr[16+l15]   - t3*sr[16+l15];
        const float o2 = t2*cr[32+l15]   + t0*sr[32+l15];
        const float o3 = t3*cr[48+l15]   + t1*sr[48+l15];
        bf16* dst = (hh < 32) ? (Qb + ((size_t)hh*2048 + row)*64)
                              : (Kb + ((size_t)(hh-32)*2048 + row)*64);
        // d-permuted positions: j -> (j>>1)*32 + pbase + (j&1)*4
        dst[pbase]          = __float2bfloat16(o0);
        dst[pbase + 4]      = __float2bfloat16(o1);
        dst[32 + pbase]     = __float2bfloat16(o2);
        dst[32 + pbase + 4] = __float2bfloat16(o3);
      } else {
        bf16* dst = Vb + ((size_t)(hh-40)*2048 + row)*64;
        dst[l15]      = __float2bfloat16(v0);
        dst[16 + l15] = __float2bfloat16(v1);
        dst[32 + l15] = __float2bfloat16(v2);
        dst[48 + l15] = __float2bfloat16(v3);
      }
    }
  }
}

// ---------------- out-proj GEMM: direct f32 store, b128 frags, depth-2 prefetch ----------------
__global__ __launch_bounds__(256) void k_gemm_out(const bf16* __restrict__ A, const bf16* __restrict__ Bt,
                                                  float* __restrict__ C, int M, int N, int K, int ldc) {
  __shared__ bf16 Asm[3][128*32];
  __shared__ bf16 Bsm[3][128*32];
  const int t = threadIdx.x;
  const int lane = t & 63, w = t >> 6;
  const int wr = w >> 1, wc = w & 1;
  const int m0 = blockIdx.y*128, n0 = blockIdx.x*128;
  const int l15 = lane & 15;
  const int g16 = (lane >> 4) << 4;

  f32x4 acc[4][4];
  #pragma unroll
  for (int i = 0; i < 4; ++i)
    #pragma unroll
    for (int j = 0; j < 4; ++j) acc[i][j] = 0.f;

  const char* Ab = (const char*)A;
  const char* Bb = (const char*)Bt;
  const int off  = t*16;
  const int srow = off >> 6;
  const int scolb = (((off >> 4) & 3) ^ ((srow >> 1) & 3)) << 4;

  const size_t arow0 = (size_t)(m0+srow)*K, arow1 = (size_t)(m0+srow+64)*K;
  const size_t brow0 = (size_t)(n0+srow)*K, brow1 = (size_t)(n0+srow+64)*K;

#define STAGE(buf, kk)  do {                                          \
    gload16(Ab + (arow0 + (kk))*2 + scolb, (char*)Asm[buf] + off);    \
    gload16(Ab + (arow1 + (kk))*2 + scolb, (char*)Asm[buf] + off + 4096); \
    gload16(Bb + (brow0 + (kk))*2 + scolb, (char*)Bsm[buf] + off);    \
    gload16(Bb + (brow1 + (kk))*2 + scolb, (char*)Bsm[buf] + off + 4096); \
  } while (0)

  const int nsteps = K >> 5;
  STAGE(0, 0);
  STAGE(1, 32);

  for (int it = 0; it < nsteps; ++it) {
    if (it + 2 < nsteps) {
      STAGE((it + 2) % 3, (it + 2) << 5);
      asm volatile("s_waitcnt vmcnt(8)" ::: "memory");
    } else if (it + 1 < nsteps) {
      asm volatile("s_waitcnt vmcnt(4)" ::: "memory");
    } else {
      asm volatile("s_waitcnt vmcnt(0)" ::: "memory");
    }
    __builtin_amdgcn_s_barrier();
    __builtin_amdgcn_sched_barrier(0);

    const char* Ac = (const char*)Asm[it % 3];
    const char* Bc = (const char*)Bsm[it % 3];
    short8v a[4], b[4];
    #pragma unroll
    for (int i = 0; i < 4; ++i) {
      const int arow = wr*64 + i*16 + l15;
      a[i] = *(const short8v*)(Ac + arow*64 + (g16 ^ (((arow >> 1) & 3) << 4)));
      const int brow = wc*64 + i*16 + l15;
      b[i] = *(const short8v*)(Bc + brow*64 + (g16 ^ (((brow >> 1) & 3) << 4)));
    }
    #pragma unroll
    for (int i = 0; i < 4; ++i)
      #pragma unroll
      for (int j = 0; j < 4; ++j)
        acc[i][j] = MFMA16(a[i], b[j], acc[i][j]);
    __builtin_amdgcn_sched_barrier(0);
    __builtin_amdgcn_s_barrier();
  }
#undef STAGE

  #pragma unroll
  for (int i = 0; i < 4; ++i) {
    int row0 = m0 + wr*64 + i*16 + ((lane>>4)<<2);
    #pragma unroll
    for (int j = 0; j < 4; ++j) {
      int col = n0 + wc*64 + j*16 + l15;
      #pragma unroll
      for (int r = 0; r < 4; ++r)
        C[(size_t)(row0+r)*ldc + col] = acc[i][j][r];
    }
  }
}

// ---------------- V transpose: Vb [8][2048][64] -> Vt [8][64][2048], kv-PERMUTED cols ----------------
__global__ __launch_bounds__(256) void k_vtrans(const bf16* __restrict__ Vb, bf16* __restrict__ Vt) {
  __shared__ bf16 ts[64][72];
  const int kv = blockIdx.y;
  const int s0 = blockIdx.x*64;
  const int t  = threadIdx.x;
  const bf16* src = Vb + ((size_t)kv*2048 + s0)*64;
  #pragma unroll
  for (int ii = 0; ii < 2; ++ii) {
    int idx = ii*256 + t;
    int s = idx >> 3, d8 = (idx & 7)*8;
    *(int4*)&ts[s][d8] = *(const int4*)(src + s*64 + d8);
  }
  __syncthreads();
  #pragma unroll
  for (int ii = 0; ii < 2; ++ii) {
    int idx = ii*256 + t;
    int d = idx >> 3, sB = (idx & 7)*8;      // storage-contiguous 8 cols at sB
    // storage sB+e <- logical (sB&32) + 4*((sB>>3)&3) + (e&3) + 16*(e>>2)
    const int w32 = sB & 32, lb = ((sB >> 3) & 3) << 2;
    short8v v;
    #pragma unroll
    for (int e = 0; e < 8; ++e)
      v[e] = __builtin_bit_cast(short, ts[w32 + lb + (e & 3) + ((e >> 2) << 4)][d]);
    *(short8v*)(Vt + (size_t)kv*64*2048 + (size_t)d*2048 + s0 + sB) = v;
  }
}

// ---------------- causal flash attention v6: b128 fragments everywhere ----------------
// Q/K d-permuted, Vt kv-permuted -> every MFMA operand is ONE aligned b128 read,
// zero CAT8/repack. pb packing already matches the permuted element order.
__global__ __launch_bounds__(512) void k_attn(const bf16* __restrict__ Qb, const bf16* __restrict__ Kb,
                                              const bf16* __restrict__ Vt, bf16* __restrict__ attnb) {
  __shared__ bf16 Ksm[128][72];   // stride 144 B: 16-aligned, 2-way banks (free)
  __shared__ bf16 Vsm[64][136];   // stride 272 B: 16-aligned, 2-way banks (free)
  const int t = threadIdx.x, lane = t & 63, w = t >> 6;
  const int bid = blockIdx.x;
  const int h = bid & 31;
  const int qi = 15 - (bid >> 5);          // heavy blocks first
  const int qb0 = qi * 128;
  const int kvh = h >> 2;
  const int kb = (lane>>4)*4;
  const int kb2 = kb << 1;                 // permuted-contiguous frag base (8g)
  const int l15 = lane & 15;

  const bf16* Qh = Qb + (size_t)h*2048*64;
  const bf16* Kh = Kb + (size_t)kvh*2048*64;
  const bf16* Vh = Vt + (size_t)kvh*64*2048;

  const int qrow = qb0 + w*16 + l15;       // this lane's q-row (replicated x4 groups)
  short8v qf[2];
  #pragma unroll
  for (int kk = 0; kk < 2; ++kk)
    qf[kk] = *(const short8v*)(Qh + (size_t)qrow*64 + kk*32 + kb2);

  float m_ = -3e38f, ls = 0.f;
  f32x4 o2[4];
  #pragma unroll
  for (int j = 0; j < 4; ++j) o2[j] = 0.f;

  const int nt = qi + 1;
  for (int tt = 0; tt < nt; ++tt) {
    #pragma unroll
    for (int ii = 0; ii < 2; ++ii) {
      int idx = ii*512 + t;
      int kr = idx >> 3, kc = (idx & 7)*8;
      *(int4*)(&Ksm[kr][kc]) = *(const int4*)(Kh + ((size_t)(tt*128 + kr))*64 + kc);
      int vr = idx >> 4, vc = (idx & 15)*8;
      *(int4*)(&Vsm[vr][vc]) = *(const int4*)(Vh + (size_t)vr*2048 + tt*128 + vc);
    }
    __syncthreads();

    // S^T = K Q^T -> sAcc[j]: kv-block j (0..7), q = l15 (pre-scaled via Q)
    f32x4 sAcc[8];
    #pragma unroll
    for (int j = 0; j < 8; ++j) sAcc[j] = 0.f;
    __builtin_amdgcn_s_setprio(1);
    #pragma unroll
    for (int kk = 0; kk < 2; ++kk) {
      #pragma unroll
      for (int j = 0; j < 8; ++j) {
        short8v ak = *(const short8v*)(&Ksm[j*16 + l15][kk*32 + kb2]);
        sAcc[j] = MFMA16(ak, qf[kk], sAcc[j]);
      }
    }
    __builtin_amdgcn_s_setprio(0);

    float p[8][4];
    #pragma unroll
    for (int j = 0; j < 8; ++j)
      #pragma unroll
      for (int r = 0; r < 4; ++r) p[j][r] = sAcc[j][r];
    if (tt == nt - 1) {                      // diagonal tile: causal mask
      #pragma unroll
      for (int j = 0; j < 8; ++j) {
        #pragma unroll
        for (int r = 0; r < 4; ++r)
          if (tt*128 + j*16 + kb + r > qrow) p[j][r] = -3e38f;
      }
    }

    // row max: max3 tree + cross-group combine
    float mj[8];
    #pragma unroll
    for (int j = 0; j < 8; ++j)
      mj[j] = fmaxf(max3f(p[j][0], p[j][1], p[j][2]), p[j][3]);
    float mx = fmaxf(max3f(mj[0], mj[1], mj[2]), max3f(mj[3], mj[4], mj[5]));
    mx = max3f(mx, mj[6], mj[7]);
    mx = fmaxf(mx, __shfl_xor(mx, 16));
    mx = fmaxf(mx, __shfl_xor(mx, 32));

    // defer-max (T13): skip rescale when tile max within 8 of running max
    float mn = m_;
    if (!__all(mx <= m_ + 8.f)) {
      mn = fmaxf(m_, mx);
      float alpha = exp2f(m_ - mn);
      m_ = mn;
      ls *= alpha;
      #pragma unroll
      for (int j = 0; j < 4; ++j) o2[j] *= alpha;
    }

    float rs = 0.f;
    #pragma unroll
    for (int j = 0; j < 8; ++j)
      #pragma unroll
      for (int r = 0; r < 4; ++r) {
        float e = exp2f(p[j][r] - mn);
        p[j][r] = e;
        rs += e;
      }
    rs += __shfl_xor(rs, 16);
    rs += __shfl_xor(rs, 32);
    ls += rs;

    short8v pb[4];
    #pragma unroll
    for (int kk = 0; kk < 4; ++kk) {
      short8v v;
      v[0] = f2bs(p[2*kk][0]);   v[1] = f2bs(p[2*kk][1]);
      v[2] = f2bs(p[2*kk][2]);   v[3] = f2bs(p[2*kk][3]);
      v[4] = f2bs(p[2*kk+1][0]); v[5] = f2bs(p[2*kk+1][1]);
      v[6] = f2bs(p[2*kk+1][2]); v[7] = f2bs(p[2*kk+1][3]);
      pb[kk] = v;
    }

    // O^T += V^T P -> o2[j]: d-block j, q = l15 (V kv-permuted -> b128 frags)
    __builtin_amdgcn_s_setprio(1);
    #pragma unroll
    for (int kk = 0; kk < 4; ++kk) {
      #pragma unroll
      for (int j = 0; j < 4; ++j) {
        short8v av = *(const short8v*)(&Vsm[j*16 + l15][kk*32 + kb2]);
        o2[j] = MFMA16(av, pb[kk], o2[j]);
      }
    }
    __builtin_amdgcn_s_setprio(0);
    __syncthreads();
  }

  // write attnb in K-PERMUTED layout (out-proj A-operand)
  float inv = 1.0f / ls;
  #pragma unroll
  for (int j = 0; j < 4; ++j) {
    short4v vv;
    vv[0] = f2bs(o2[j][0]*inv); vv[1] = f2bs(o2[j][1]*inv);
    vv[2] = f2bs(o2[j][2]*inv); vv[3] = f2bs(o2[j][3]*inv);
    *(short4v*)(attnb + (size_t)qrow*2048 + h*64 + (j>>1)*32 + (kb<<1) + ((j&1)<<2)) = vv;
  }
}

extern "C" void kernel_launch(void* const* d_in, const int* in_sizes, int n_in,
                              void* d_out, int out_size, void* d_ws, size_t ws_size,
                              hipStream_t stream) {
  const float* x    = (const float*)d_in[0];
  const float* cosb = (const float*)d_in[2];
  const float* sinb = (const float*)d_in[3];
  const float* Wq   = (const float*)d_in[4];
  const float* Wk   = (const float*)d_in[5];
  const float* Wv   = (const float*)d_in[6];
  const float* Wo   = (const float*)d_in[7];
  const float* qg   = (const float*)d_in[8];
  const float* kg   = (const float*)d_in[9];
  float* out = (float*)d_out;

  char* ws = (char*)d_ws;
  bf16*  xb    = (bf16*)(ws);                    // 8 MB  K-perm (live thru QKV GEMM)
  bf16*  WqT   = (bf16*)(ws + 8388608);          // 8 MB  K-perm
  bf16*  WkT   = (bf16*)(ws + 16777216);         // 2 MB  K-perm
  bf16*  WvT   = (bf16*)(ws + 18874368);         // 2 MB  K-perm (contiguous N=3072 B-panel)
  bf16*  WoT   = (bf16*)(ws + 20971520);         // 8 MB  K-perm (live until out-proj)
  bf16*  Qb    = (bf16*)(ws + 29360128);         // 8 MB  [32][2048][64] d-perm, x SCALE2
  bf16*  Kb    = (bf16*)(ws + 37748736);         // 2 MB  [8][2048][64] d-perm
  bf16*  Vb    = (bf16*)(ws + 39845888);         // 2 MB  [8][2048][64] logical
  bf16*  Vt    = (bf16*)(ws + 41943040);         // 2 MB  [8][64][2048] kv-perm cols
  bf16*  attnb = (bf16*)(ws);                    // 8 MB  K-perm (overlays dead xb)

  k_prep<<<6656, 256, 0, stream>>>(x, Wq, Wk, Wv, Wo, xb, WqT, WkT, WvT, WoT);
  k_gemm_qkv<<<dim3(24, 16), 256, 0, stream>>>(xb, WqT, cosb, sinb, qg, kg, Qb, Kb, Vb, 2048);
  k_vtrans<<<dim3(32, 8), 256, 0, stream>>>(Vb, Vt);
  k_attn<<<512, 512, 0, stream>>>(Qb, Kb, Vt, attnb);
  k_gemm_out<<<dim3(16, 16), 256, 0, stream>>>(attnb, WoT, out, 2048, 2048, 2048, 2048);
}